// Round 1
// baseline (1553.562 us; speedup 1.0000x reference)
//
#include <hip/hip_runtime.h>
#include <hip/hip_bf16.h>

typedef __bf16 bf16x8 __attribute__((ext_vector_type(8)));
typedef float f32x4 __attribute__((ext_vector_type(4)));
typedef unsigned short ushort_t;

#define NPOS 512
#define CIN  5
#define CO   128

static __device__ __forceinline__ unsigned short f2bf(float f){
  union { __hip_bfloat16 h; unsigned short u; } cv;
  cv.h = __float2bfloat16(f);
  return cv.u;
}

// ---------------- weight fp32 -> bf16 prep ----------------
__global__ void k_prep(const float* __restrict__ w2, const float* __restrict__ w3,
                       const float* __restrict__ w4, ushort_t* __restrict__ o){
  int i = blockIdx.x*256 + threadIdx.x;   // grid covers 163840 exactly
  if (i < 65536)        o[i] = f2bf(w2[i]);
  else if (i < 131072)  o[i] = f2bf(w3[i-65536]);
  else                  o[i] = f2bf(w4[i-131072]);
}

// ---------------- fused conv1..conv4 ----------------
// LDS activation layout: element (n, c) at  n*256 + ((c>>3) ^ (n&7))*8 + (c&7)
// (16B-chunk XOR swizzle -> bank-uniform ds_read_b128 for MFMA A-fragments)

template<int NSD, bool RELU>
static __device__ __forceinline__ void gemm_tile(
    const ushort_t* __restrict__ Wb, const float* __restrict__ bias,
    const ushort_t* __restrict__ src, ushort_t* __restrict__ dst,
    int wave, int lane)
{
  const int m = lane & 15, quad = lane >> 4;
  const int d0 = wave * (NSD*16);
  f32x4 acc[4][NSD];
  #pragma unroll
  for (int sn=0;sn<4;sn++)
    #pragma unroll
    for (int sd=0;sd<NSD;sd++)
      acc[sn][sd] = (f32x4){0.f,0.f,0.f,0.f};

  #pragma unroll
  for (int ks=0; ks<8; ks++){
    bf16x8 a[4];
    #pragma unroll
    for (int sn=0;sn<4;sn++){
      int row = sn*16 + m;
      int kc  = ks*4 + quad;
      a[sn] = *(const bf16x8*)(src + row*256 + ((kc ^ (row&7)) << 3));
    }
    #pragma unroll
    for (int sd=0;sd<NSD;sd++){
      int d = d0 + sd*16 + m;
      bf16x8 bb = *(const bf16x8*)(Wb + d*256 + ks*32 + quad*8);
      #pragma unroll
      for (int sn=0;sn<4;sn++)
        acc[sn][sd] = __builtin_amdgcn_mfma_f32_16x16x32_bf16(a[sn], bb, acc[sn][sd], 0,0,0);
    }
  }
  #pragma unroll
  for (int sd=0;sd<NSD;sd++){
    int d = d0 + sd*16 + m;
    float bv = bias[d];
    #pragma unroll
    for (int sn=0;sn<4;sn++){
      #pragma unroll
      for (int rg=0;rg<4;rg++){
        int n = sn*16 + quad*4 + rg;
        float v = acc[sn][sd][rg] + bv;
        if (RELU) v = fmaxf(v, 0.f);
        dst[n*256 + (((d>>3) ^ (n&7)) << 3) + (d&7)] = f2bf(v);
      }
    }
  }
}

// layer 4: Dout=128, no relu, (acc+b4)/512*mask, write transposed (c-major, stride 72)
static __device__ __forceinline__ void gemm_tile4(
    const ushort_t* __restrict__ Wb, const float* __restrict__ bias,
    const float* __restrict__ maskrow,
    const ushort_t* __restrict__ src, ushort_t* __restrict__ dst72,
    int wave, int lane)
{
  const int m = lane & 15, quad = lane >> 4;
  const int d0 = wave * 32;
  f32x4 acc[4][2];
  #pragma unroll
  for (int sn=0;sn<4;sn++){ acc[sn][0] = (f32x4){0.f,0.f,0.f,0.f}; acc[sn][1] = (f32x4){0.f,0.f,0.f,0.f}; }

  #pragma unroll
  for (int ks=0; ks<8; ks++){
    bf16x8 a[4];
    #pragma unroll
    for (int sn=0;sn<4;sn++){
      int row = sn*16 + m;
      int kc  = ks*4 + quad;
      a[sn] = *(const bf16x8*)(src + row*256 + ((kc ^ (row&7)) << 3));
    }
    #pragma unroll
    for (int sd=0;sd<2;sd++){
      int d = d0 + sd*16 + m;
      bf16x8 bb = *(const bf16x8*)(Wb + d*256 + ks*32 + quad*8);
      #pragma unroll
      for (int sn=0;sn<4;sn++)
        acc[sn][sd] = __builtin_amdgcn_mfma_f32_16x16x32_bf16(a[sn], bb, acc[sn][sd], 0,0,0);
    }
  }
  #pragma unroll
  for (int sd=0;sd<2;sd++){
    int d = d0 + sd*16 + m;
    float bv = bias[d];
    #pragma unroll
    for (int sn=0;sn<4;sn++){
      #pragma unroll
      for (int rg=0;rg<4;rg++){
        int n = sn*16 + quad*4 + rg;
        float v = (acc[sn][sd][rg] + bv) * (1.0f/512.0f) * maskrow[n];
        dst72[d*72 + n] = f2bf(v);
      }
    }
  }
}

__global__ __launch_bounds__(256,2) void k_fused(
  const float* __restrict__ x, const float* __restrict__ mask,
  const float* __restrict__ w1, const float* __restrict__ b1,
  const ushort_t* __restrict__ w2b, const float* __restrict__ b2,
  const ushort_t* __restrict__ w3b, const float* __restrict__ b3,
  const ushort_t* __restrict__ w4b, const float* __restrict__ b4,
  ushort_t* __restrict__ h4)
{
  __shared__ __align__(16) ushort_t A [64*256];
  __shared__ __align__(16) ushort_t Bf[64*256];
  __shared__ __align__(16) float xs[CIN][64];
  const int t    = threadIdx.x;
  const int bid  = blockIdx.x;
  const int b    = bid >> 3;
  const int n0   = (bid & 7) << 6;
  const int wave = t >> 6, lane = t & 63;

  if (t < 80){
    int c = t >> 4, ch = t & 15;
    *(float4*)&xs[c][ch*4] = *(const float4*)(x + ((size_t)b*CIN + c)*NPOS + n0 + ch*4);
  }
  __syncthreads();

  // layer 1 (K=5, VALU) -> A
  #pragma unroll
  for (int i=0;i<8;i++){
    int task = i*256 + t;
    int n = task >> 5, c8 = task & 31;
    // rows c8*8 .. c8*8+7 of w1 are 40 contiguous floats
    float wv[40];
    #pragma unroll
    for (int q=0;q<10;q++)
      *(float4*)&wv[q*4] = *(const float4*)(w1 + c8*40 + q*4);
    float acc1[8];
    #pragma unroll
    for (int j=0;j<8;j++) acc1[j] = b1[c8*8+j];
    #pragma unroll
    for (int c=0;c<CIN;c++){
      float xv = xs[c][n];
      #pragma unroll
      for (int j=0;j<8;j++) acc1[j] = fmaf(wv[j*CIN + c], xv, acc1[j]);
    }
    unsigned u[4];
    #pragma unroll
    for (int j=0;j<4;j++){
      unsigned lo = f2bf(fmaxf(acc1[2*j  ],0.f));
      unsigned hi = f2bf(fmaxf(acc1[2*j+1],0.f));
      u[j] = lo | (hi<<16);
    }
    *(uint4*)&A[n*256 + ((c8 ^ (n&7)) << 3)] = make_uint4(u[0],u[1],u[2],u[3]);
  }
  __syncthreads();

  gemm_tile<4,true>(w2b, b2, A,  Bf, wave, lane);
  __syncthreads();
  gemm_tile<4,true>(w3b, b3, Bf, A,  wave, lane);
  __syncthreads();
  gemm_tile4(w4b, b4, mask + (size_t)b*NPOS + n0, A, Bf, wave, lane);
  __syncthreads();

  // Bf holds (c=128 rows, stride 72, 64 n each); store to h4[b][c][n0..n0+63]
  #pragma unroll
  for (int i=0;i<4;i++){
    int L = i*256 + t;
    int c = L >> 3, ch = L & 7;
    uint4 vv = *(const uint4*)&Bf[c*72 + ch*8];
    *(uint4*)(h4 + ((size_t)b*CO + c)*NPOS + n0 + ch*8) = vv;
  }
}

// ---------------- sort + pool ----------------
// one wave per (b,c) row: 512 elems, 8/lane, full bitonic descending
__global__ void k_pool(const ushort_t* __restrict__ h4, const float* __restrict__ pw,
                       float* __restrict__ out)
{
  const int lane = threadIdx.x & 63;
  const int wave = threadIdx.x >> 6;
  const size_t r = (size_t)blockIdx.x*4 + wave;    // 0..131071
  const int b = (int)(r >> 7), c = (int)(r & 127);

  uint4 raw = *(const uint4*)(h4 + r*NPOS + lane*8);
  float v[8];
  {
    unsigned ww[4] = {raw.x, raw.y, raw.z, raw.w};
    #pragma unroll
    for (int i=0;i<4;i++){
      union {float f; unsigned u;} lo, hi;
      lo.u = ww[i] << 16;
      hi.u = ww[i] & 0xffff0000u;
      v[2*i] = lo.f; v[2*i+1] = hi.f;
    }
  }

  #pragma unroll
  for (int k=2; k<=512; k<<=1){
    #pragma unroll
    for (int j=k>>1; j>=8; j>>=1){            // cross-lane steps
      const int lm = j >> 3;
      const bool lower = (lane & lm) == 0;
      const bool desc  = ((lane*8) & k) == 0; // k>=16 here: r-bits irrelevant
      #pragma unroll
      for (int rr=0;rr<8;rr++){
        float o = __shfl_xor(v[rr], lm);
        v[rr] = (desc == lower) ? fmaxf(v[rr], o) : fminf(v[rr], o);
      }
    }
    #pragma unroll
    for (int j = ((k>>1) < 8 ? (k>>1) : 4); j>=1; j>>=1){   // in-lane steps
      #pragma unroll
      for (int rr=0;rr<8;rr++){
        if ((rr & j) == 0){
          const bool desc = (((lane*8 + rr) & k) == 0);
          float a = v[rr], b2 = v[rr|j];
          bool sw = desc ? (a < b2) : (a > b2);
          if (sw){ v[rr] = b2; v[rr|j] = a; }
        }
      }
    }
  }

  float s = 0.f;
  #pragma unroll
  for (int rr=0;rr<8;rr++){
    int e = lane*8 + rr;
    float pos = (float)e * (20.0f/511.0f);
    int idx = (int)pos; if (idx > 20) idx = 20;
    float frac = pos - (float)idx;
    int i2 = (idx+1 > 20) ? 20 : idx+1;
    float wl = pw[c*21 + idx], wr = pw[c*21 + i2];
    s += v[rr] * (wl + frac*(wr-wl));
  }
  #pragma unroll
  for (int off=32; off>=1; off>>=1) s += __shfl_xor(s, off);
  if (lane == 0) out[b*129 + c] = s;
}

// ---------------- size feature ----------------
__global__ void k_size(const float* __restrict__ mask, float* __restrict__ out){
  const int b = blockIdx.x, lane = threadIdx.x;
  float s = 0.f;
  #pragma unroll
  for (int i=0;i<8;i++) s += mask[(size_t)b*NPOS + i*64 + lane];
  #pragma unroll
  for (int off=32; off>=1; off>>=1) s += __shfl_xor(s, off);
  if (lane == 0) out[b*129 + 128] = s * (1.0f/128.0f);  // mean*4 = sum/512*4
}

extern "C" void kernel_launch(void* const* d_in, const int* in_sizes, int n_in,
                              void* d_out, int out_size, void* d_ws, size_t ws_size,
                              hipStream_t stream){
  const float* x    = (const float*)d_in[0];
  const float* mask = (const float*)d_in[1];
  const float* w1   = (const float*)d_in[2];
  const float* b1   = (const float*)d_in[3];
  const float* w2   = (const float*)d_in[4];
  const float* b2   = (const float*)d_in[5];
  const float* w3   = (const float*)d_in[6];
  const float* b3   = (const float*)d_in[7];
  const float* w4   = (const float*)d_in[8];
  const float* b4   = (const float*)d_in[9];
  const float* pw   = (const float*)d_in[10];
  float* out = (float*)d_out;

  // ws: h4 bf16 (1024*128*512 = 128MB) | w2b | w3b | w4b
  ushort_t* h4  = (ushort_t*)d_ws;
  ushort_t* w2b = h4 + (size_t)1024*CO*NPOS;
  ushort_t* w3b = w2b + 65536;
  ushort_t* w4b = w3b + 65536;

  k_prep <<<640,   256, 0, stream>>>(w2, w3, w4, w2b);
  k_fused<<<8192,  256, 0, stream>>>(x, mask, w1, b1, w2b, b2, w3b, b3, w4b, b4, h4);
  k_pool <<<32768, 256, 0, stream>>>(h4, pw, out);
  k_size <<<1024,  64,  0, stream>>>(mask, out);
}

// Round 2
// 739.577 us; speedup vs baseline: 2.1006x; 2.1006x over previous
//
#include <hip/hip_runtime.h>
#include <hip/hip_bf16.h>

typedef __bf16 bf16x8 __attribute__((ext_vector_type(8)));
typedef float f32x4 __attribute__((ext_vector_type(4)));
typedef unsigned short ushort_t;

#define NPOS 512
#define CIN  5
#define CO   128

static __device__ __forceinline__ unsigned short f2bf(float f){
  union { __hip_bfloat16 h; unsigned short u; } cv;
  cv.h = __float2bfloat16(f);
  return cv.u;
}

// ---------------- weight fp32 -> bf16 prep ----------------
__global__ void k_prep(const float* __restrict__ w2, const float* __restrict__ w3,
                       const float* __restrict__ w4, ushort_t* __restrict__ o){
  int i = blockIdx.x*256 + threadIdx.x;   // grid covers 163840 exactly
  if (i < 65536)        o[i] = f2bf(w2[i]);
  else if (i < 131072)  o[i] = f2bf(w3[i-65536]);
  else                  o[i] = f2bf(w4[i-131072]);
}

// ---------------- fused conv1..conv4 ----------------
// LDS activation layout: element (n, c) at  n*256 + ((c>>3) ^ (n&7))*8 + (c&7)
// (16B-chunk XOR swizzle -> bank-uniform ds_read_b128 for MFMA A-fragments)
//
// W fragments for a whole layer are register-prefetched (wr[8][4] = 128 VGPR,
// ks-major issue order so in-order vmcnt return lets ks=0 MFMAs start after
// 4 loads). Next layer's loads issue right after the current layer's MFMAs,
// hidden behind epilogue + barrier. This removes the per-(ks,sd) L2-latency
// serialization that made R1 latency-bound (MfmaUtil 5.6%).

template<int NSD>
static __device__ __forceinline__ void load_w(bf16x8 (&wr)[8][4],
    const ushort_t* __restrict__ Wb, int wave, int lane){
  const int m = lane & 15, quad = lane >> 4;
  const int d0 = wave * (NSD*16);
  #pragma unroll
  for (int ks=0; ks<8; ks++)
    #pragma unroll
    for (int sd=0; sd<NSD; sd++)
      wr[ks][sd] = *(const bf16x8*)(Wb + (d0 + sd*16 + m)*256 + ks*32 + quad*8);
}

template<int NSD>
static __device__ __forceinline__ void mfma_phase(const bf16x8 (&wr)[8][4],
    const ushort_t* __restrict__ src, f32x4 (&acc)[4][4], int lane){
  const int m = lane & 15, quad = lane >> 4;
  #pragma unroll
  for (int sn=0;sn<4;sn++)
    #pragma unroll
    for (int sd=0;sd<NSD;sd++)
      acc[sn][sd] = (f32x4){0.f,0.f,0.f,0.f};
  #pragma unroll
  for (int ks=0; ks<8; ks++){
    bf16x8 a[4];
    #pragma unroll
    for (int sn=0;sn<4;sn++){
      int row = sn*16 + m;
      int kc  = ks*4 + quad;
      a[sn] = *(const bf16x8*)(src + row*256 + ((kc ^ (row&7)) << 3));
    }
    #pragma unroll
    for (int sd=0;sd<NSD;sd++)
      #pragma unroll
      for (int sn=0;sn<4;sn++)
        acc[sn][sd] = __builtin_amdgcn_mfma_f32_16x16x32_bf16(a[sn], wr[ks][sd], acc[sn][sd], 0,0,0);
  }
}

static __device__ __forceinline__ void epilogue_relu(const f32x4 (&acc)[4][4],
    const float* __restrict__ bias, ushort_t* __restrict__ dst, int wave, int lane){
  const int m = lane & 15, quad = lane >> 4;
  const int d0 = wave * 64;
  #pragma unroll
  for (int sd=0;sd<4;sd++){
    int d = d0 + sd*16 + m;
    float bv = bias[d];
    #pragma unroll
    for (int sn=0;sn<4;sn++){
      #pragma unroll
      for (int rg=0;rg<4;rg++){
        int n = sn*16 + quad*4 + rg;
        float v = fmaxf(acc[sn][sd][rg] + bv, 0.f);
        dst[n*256 + (((d>>3) ^ (n&7)) << 3) + (d&7)] = f2bf(v);
      }
    }
  }
}

// layer 4: (acc+b4)/512*mask, write transposed (c-major, stride 72), 8B packed
static __device__ __forceinline__ void epilogue4(const f32x4 (&acc)[4][4],
    const float* __restrict__ bias, const float* __restrict__ maskrow,
    ushort_t* __restrict__ dst72, int wave, int lane){
  const int m = lane & 15, quad = lane >> 4;
  const int d0 = wave * 32;
  #pragma unroll
  for (int sd=0;sd<2;sd++){
    int d = d0 + sd*16 + m;
    float bv = bias[d];
    #pragma unroll
    for (int sn=0;sn<4;sn++){
      ushort4 p;
      #pragma unroll
      for (int rg=0;rg<4;rg++){
        int n = sn*16 + quad*4 + rg;
        float v = (acc[sd? 0:0][0][0]*0.f + acc[sn][sd][rg] + bv) * (1.0f/512.0f) * maskrow[n];
        ushort_t u = f2bf(v);
        if (rg==0) p.x=u; else if (rg==1) p.y=u; else if (rg==2) p.z=u; else p.w=u;
      }
      *(ushort4*)&dst72[d*72 + sn*16 + quad*4] = p;
    }
  }
}

__global__ __launch_bounds__(256,2) void k_fused(
  const float* __restrict__ x, const float* __restrict__ mask,
  const float* __restrict__ w1, const float* __restrict__ b1,
  const ushort_t* __restrict__ w2b, const float* __restrict__ b2,
  const ushort_t* __restrict__ w3b, const float* __restrict__ b3,
  const ushort_t* __restrict__ w4b, const float* __restrict__ b4,
  ushort_t* __restrict__ h4)
{
  __shared__ __align__(16) ushort_t A [64*256];
  __shared__ __align__(16) ushort_t Bf[64*256];
  __shared__ __align__(16) float xs[CIN][64];
  const int t    = threadIdx.x;
  const int bid  = blockIdx.x;
  const int b    = bid >> 3;
  const int n0   = (bid & 7) << 6;
  const int wave = t >> 6, lane = t & 63;

  bf16x8 wr[8][4];      // whole-layer W fragment cache (128 VGPR)
  f32x4  acc[4][4];

  if (t < 80){
    int c = t >> 4, ch = t & 15;
    *(float4*)&xs[c][ch*4] = *(const float4*)(x + ((size_t)b*CIN + c)*NPOS + n0 + ch*4);
  }

  // layer-1 per-thread weights: c8 = (i*256+t)&31 == t&31 for all i -> hoist
  const int c8 = t & 31, nb = t >> 5;
  float wv[40];
  #pragma unroll
  for (int q=0;q<10;q++)
    *(float4*)&wv[q*4] = *(const float4*)(w1 + c8*40 + q*4);
  float bs1[8];
  #pragma unroll
  for (int j=0;j<8;j++) bs1[j] = b1[c8*8+j];

  load_w<4>(wr, w2b, wave, lane);          // W2 in flight during layer 1

  __syncthreads();                         // xs ready

  // layer 1 (K=5, VALU) -> A
  #pragma unroll
  for (int i=0;i<8;i++){
    int n = i*8 + nb;
    float acc1[8];
    #pragma unroll
    for (int j=0;j<8;j++) acc1[j] = bs1[j];
    #pragma unroll
    for (int c=0;c<CIN;c++){
      float xv = xs[c][n];
      #pragma unroll
      for (int j=0;j<8;j++) acc1[j] = fmaf(wv[j*CIN + c], xv, acc1[j]);
    }
    unsigned u[4];
    #pragma unroll
    for (int j=0;j<4;j++){
      unsigned lo = f2bf(fmaxf(acc1[2*j  ],0.f));
      unsigned hi = f2bf(fmaxf(acc1[2*j+1],0.f));
      u[j] = lo | (hi<<16);
    }
    *(uint4*)&A[n*256 + ((c8 ^ (n&7)) << 3)] = make_uint4(u[0],u[1],u[2],u[3]);
  }
  __syncthreads();

  mfma_phase<4>(wr, A, acc, lane);         // layer 2
  load_w<4>(wr, w3b, wave, lane);          // W3 in flight during epilogue+barrier
  epilogue_relu(acc, b2, Bf, wave, lane);
  __syncthreads();

  mfma_phase<4>(wr, Bf, acc, lane);        // layer 3
  load_w<2>(wr, w4b, wave, lane);          // W4 in flight
  epilogue_relu(acc, b3, A, wave, lane);
  __syncthreads();

  mfma_phase<2>(wr, A, acc, lane);         // layer 4
  epilogue4(acc, b4, mask + (size_t)b*NPOS + n0, Bf, wave, lane);
  __syncthreads();

  // Bf holds (c=128 rows, stride 72, 64 n each); store to h4[b][c][n0..n0+63]
  #pragma unroll
  for (int i=0;i<4;i++){
    int L = i*256 + t;
    int c = L >> 3, ch = L & 7;
    uint4 vv = *(const uint4*)&Bf[c*72 + ch*8];
    *(uint4*)(h4 + ((size_t)b*CO + c)*NPOS + n0 + ch*8) = vv;
  }
}

// ---------------- sort + pool ----------------
// one wave per (b,c) row: 512 elems, 8/lane, full bitonic descending
__global__ void k_pool(const ushort_t* __restrict__ h4, const float* __restrict__ pw,
                       float* __restrict__ out)
{
  const int lane = threadIdx.x & 63;
  const int wave = threadIdx.x >> 6;
  const size_t r = (size_t)blockIdx.x*4 + wave;    // 0..131071
  const int b = (int)(r >> 7), c = (int)(r & 127);

  uint4 raw = *(const uint4*)(h4 + r*NPOS + lane*8);
  float v[8];
  {
    unsigned ww[4] = {raw.x, raw.y, raw.z, raw.w};
    #pragma unroll
    for (int i=0;i<4;i++){
      union {float f; unsigned u;} lo, hi;
      lo.u = ww[i] << 16;
      hi.u = ww[i] & 0xffff0000u;
      v[2*i] = lo.f; v[2*i+1] = hi.f;
    }
  }

  #pragma unroll
  for (int k=2; k<=512; k<<=1){
    #pragma unroll
    for (int j=k>>1; j>=8; j>>=1){            // cross-lane steps
      const int lm = j >> 3;
      const bool lower = (lane & lm) == 0;
      const bool desc  = ((lane*8) & k) == 0; // k>=16 here: r-bits irrelevant
      #pragma unroll
      for (int rr=0;rr<8;rr++){
        float o = __shfl_xor(v[rr], lm);
        v[rr] = (desc == lower) ? fmaxf(v[rr], o) : fminf(v[rr], o);
      }
    }
    #pragma unroll
    for (int j = ((k>>1) < 8 ? (k>>1) : 4); j>=1; j>>=1){   // in-lane steps
      #pragma unroll
      for (int rr=0;rr<8;rr++){
        if ((rr & j) == 0){
          const bool desc = (((lane*8 + rr) & k) == 0);
          float a = v[rr], b2 = v[rr|j];
          bool sw = desc ? (a < b2) : (a > b2);
          if (sw){ v[rr] = b2; v[rr|j] = a; }
        }
      }
    }
  }

  float s = 0.f;
  #pragma unroll
  for (int rr=0;rr<8;rr++){
    int e = lane*8 + rr;
    float pos = (float)e * (20.0f/511.0f);
    int idx = (int)pos; if (idx > 20) idx = 20;
    float frac = pos - (float)idx;
    int i2 = (idx+1 > 20) ? 20 : idx+1;
    float wl = pw[c*21 + idx], wr = pw[c*21 + i2];
    s += v[rr] * (wl + frac*(wr-wl));
  }
  #pragma unroll
  for (int off=32; off>=1; off>>=1) s += __shfl_xor(s, off);
  if (lane == 0) out[b*129 + c] = s;
}

// ---------------- size feature ----------------
__global__ void k_size(const float* __restrict__ mask, float* __restrict__ out){
  const int b = blockIdx.x, lane = threadIdx.x;
  float s = 0.f;
  #pragma unroll
  for (int i=0;i<8;i++) s += mask[(size_t)b*NPOS + i*64 + lane];
  #pragma unroll
  for (int off=32; off>=1; off>>=1) s += __shfl_xor(s, off);
  if (lane == 0) out[b*129 + 128] = s * (1.0f/128.0f);  // mean*4 = sum/512*4
}

extern "C" void kernel_launch(void* const* d_in, const int* in_sizes, int n_in,
                              void* d_out, int out_size, void* d_ws, size_t ws_size,
                              hipStream_t stream){
  const float* x    = (const float*)d_in[0];
  const float* mask = (const float*)d_in[1];
  const float* w1   = (const float*)d_in[2];
  const float* b1   = (const float*)d_in[3];
  const float* w2   = (const float*)d_in[4];
  const float* b2   = (const float*)d_in[5];
  const float* w3   = (const float*)d_in[6];
  const float* b3   = (const float*)d_in[7];
  const float* w4   = (const float*)d_in[8];
  const float* b4   = (const float*)d_in[9];
  const float* pw   = (const float*)d_in[10];
  float* out = (float*)d_out;

  // ws: h4 bf16 (1024*128*512 = 128MB) | w2b | w3b | w4b
  ushort_t* h4  = (ushort_t*)d_ws;
  ushort_t* w2b = h4 + (size_t)1024*CO*NPOS;
  ushort_t* w3b = w2b + 65536;
  ushort_t* w4b = w3b + 65536;

  k_prep <<<640,   256, 0, stream>>>(w2, w3, w4, w2b);
  k_fused<<<8192,  256, 0, stream>>>(x, mask, w1, b1, w2b, b2, w3b, b3, w4b, b4, h4);
  k_pool <<<32768, 256, 0, stream>>>(h4, pw, out);
  k_size <<<1024,  64,  0, stream>>>(mask, out);
}

// Round 3
// 712.976 us; speedup vs baseline: 2.1790x; 1.0373x over previous
//
#include <hip/hip_runtime.h>
#include <hip/hip_bf16.h>

typedef __bf16 bf16x8 __attribute__((ext_vector_type(8)));
typedef float f32x4 __attribute__((ext_vector_type(4)));
typedef unsigned short ushort_t;

#define NPOS 512
#define CIN  5
#define CO   128

static __device__ __forceinline__ unsigned short f2bf(float f){
  union { __hip_bfloat16 h; unsigned short u; } cv;
  cv.h = __float2bfloat16(f);
  return cv.u;
}

// ---------------- weight fp32 -> bf16 prep ----------------
__global__ void k_prep(const float* __restrict__ w2, const float* __restrict__ w3,
                       const float* __restrict__ w4, ushort_t* __restrict__ o){
  int i = blockIdx.x*256 + threadIdx.x;   // grid covers 163840 exactly
  if (i < 65536)        o[i] = f2bf(w2[i]);
  else if (i < 131072)  o[i] = f2bf(w3[i-65536]);
  else                  o[i] = f2bf(w4[i-131072]);
}

// ---------------- fused conv1..conv4 ----------------
// Fragment-major LDS act layout: element (n,c) lives in 16B chunk
//   chunk(n,c) = (n>>4)*512 + (c>>5)*64 + ((c>>3)&3)*16 + (n&15),  j = c&7
// MFMA A-read for (sn,ks): chunk = sn*512 + ks*64 + lane  -> lane-sequential,
// bank-perfect ds_read_b128 (R2's swizzle left 8-way conflicts, 1.4e7 cyc).
// 512-thread blocks, wave owns 32-wide d-slice: wr[8][2]=64 VGPR + acc 32
// -> ~120 regs/wave -> 4 waves/SIMD (R2 was reg+LDS capped at 2).

template<int NSD>
static __device__ __forceinline__ void load_w(bf16x8 (&wr)[8][2],
    const ushort_t* __restrict__ Wb, int wave, int lane){
  const int m = lane & 15, quad = lane >> 4;
  const int d0 = wave * (NSD*16);
  #pragma unroll
  for (int ks=0; ks<8; ks++)
    #pragma unroll
    for (int sd=0; sd<NSD; sd++)
      wr[ks][sd] = *(const bf16x8*)(Wb + (d0 + sd*16 + m)*256 + ks*32 + quad*8);
}

template<int NSD>
static __device__ __forceinline__ void mfma_phase(const bf16x8 (&wr)[8][2],
    const ushort_t* __restrict__ src, f32x4 (&acc)[4][2], int lane){
  #pragma unroll
  for (int sn=0;sn<4;sn++)
    #pragma unroll
    for (int sd=0;sd<NSD;sd++)
      acc[sn][sd] = (f32x4){0.f,0.f,0.f,0.f};
  #pragma unroll
  for (int ks=0; ks<8; ks++){
    bf16x8 a[4];
    #pragma unroll
    for (int sn=0;sn<4;sn++)
      a[sn] = *(const bf16x8*)(src + ((sn*512 + ks*64 + lane) << 3));
    #pragma unroll
    for (int sd=0;sd<NSD;sd++)
      #pragma unroll
      for (int sn=0;sn<4;sn++)
        acc[sn][sd] = __builtin_amdgcn_mfma_f32_16x16x32_bf16(a[sn], wr[ks][sd], acc[sn][sd], 0,0,0);
  }
}

// layers 2/3: +bias, relu, write back into fragment-major layout (u16 scalar,
// ~4-way worst-case banks = acceptable)
static __device__ __forceinline__ void epilogue_relu(const f32x4 (&acc)[4][2],
    const float* __restrict__ bias, ushort_t* __restrict__ dst, int wave, int lane){
  const int m = lane & 15, quad = lane >> 4;
  const int d0 = wave * 32;
  #pragma unroll
  for (int sd=0;sd<2;sd++){
    int d = d0 + sd*16 + m;
    float bv = bias[d];
    int colbase = (d>>5)*64 + ((d>>3)&3)*16;   // chunk col part for c=d
    int j = d & 7;
    #pragma unroll
    for (int sn=0;sn<4;sn++){
      #pragma unroll
      for (int rg=0;rg<4;rg++){
        float v = fmaxf(acc[sn][sd][rg] + bv, 0.f);
        dst[((sn*512 + colbase + quad*4 + rg) << 3) + j] = f2bf(v);
      }
    }
  }
}

__global__ __launch_bounds__(512,4) void k_fused(
  const float* __restrict__ x, const float* __restrict__ mask,
  const float* __restrict__ w1, const float* __restrict__ b1,
  const ushort_t* __restrict__ w2b, const float* __restrict__ b2,
  const ushort_t* __restrict__ w3b, const float* __restrict__ b3,
  const ushort_t* __restrict__ w4b, const float* __restrict__ b4,
  ushort_t* __restrict__ h4)
{
  __shared__ __align__(16) ushort_t A [64*256];
  __shared__ __align__(16) ushort_t Bf[64*256];
  __shared__ __align__(16) float xs[CIN][64];
  const int t    = threadIdx.x;
  const int bid  = blockIdx.x;
  const int b    = bid >> 3;
  const int n0   = (bid & 7) << 6;
  const int wave = t >> 6, lane = t & 63;

  bf16x8 wr[8][2];
  f32x4  acc[4][2];

  if (t < 80){
    int c = t >> 4, ch = t & 15;
    *(float4*)&xs[c][ch*4] = *(const float4*)(x + ((size_t)b*CIN + c)*NPOS + n0 + ch*4);
  }

  // layer-1: thread owns c-octet oct=(t>>4)&31 over n = i*16 + (t&15), i=0..3
  {
    const int oct = (t >> 4) & 31, mn = t & 15;
    float wv[40];
    #pragma unroll
    for (int q=0;q<10;q++)
      *(float4*)&wv[q*4] = *(const float4*)(w1 + oct*40 + q*4);
    float bs1[8];
    *(float4*)&bs1[0] = *(const float4*)(b1 + oct*8);
    *(float4*)&bs1[4] = *(const float4*)(b1 + oct*8 + 4);

    __syncthreads();                       // xs ready

    #pragma unroll
    for (int i=0;i<4;i++){
      int n = i*16 + mn;
      float acc1[8];
      #pragma unroll
      for (int j=0;j<8;j++) acc1[j] = bs1[j];
      #pragma unroll
      for (int c=0;c<CIN;c++){
        float xv = xs[c][n];
        #pragma unroll
        for (int j=0;j<8;j++) acc1[j] = fmaf(wv[j*CIN + c], xv, acc1[j]);
      }
      unsigned u[4];
      #pragma unroll
      for (int j=0;j<4;j++){
        unsigned lo = f2bf(fmaxf(acc1[2*j  ],0.f));
        unsigned hi = f2bf(fmaxf(acc1[2*j+1],0.f));
        u[j] = lo | (hi<<16);
      }
      // chunk = i*512 + t : lane-sequential b128 write
      *(uint4*)&A[(i*512 + t) << 3] = make_uint4(u[0],u[1],u[2],u[3]);
    }
  }

  load_w<2>(wr, w2b, wave, lane);          // W2 in flight across barrier
  __syncthreads();

  mfma_phase<2>(wr, A, acc, lane);         // layer 2
  load_w<2>(wr, w3b, wave, lane);          // W3 in flight during epilogue
  epilogue_relu(acc, b2, Bf, wave, lane);
  __syncthreads();

  mfma_phase<2>(wr, Bf, acc, lane);        // layer 3
  load_w<1>(wr, w4b, wave, lane);          // W4 in flight
  epilogue_relu(acc, b3, A, wave, lane);
  __syncthreads();

  mfma_phase<1>(wr, A, acc, lane);         // layer 4 (wave owns 16 d)
  {
    const int m = lane & 15, quad = lane >> 4;
    const int d = wave*16 + m;
    const float bv = b4[d];
    const float* maskrow = mask + (size_t)b*NPOS + n0;
    ushort_t* rowp = h4 + ((size_t)b*CO + d)*NPOS + n0;
    #pragma unroll
    for (int sn=0;sn<4;sn++){
      float4 mr = *(const float4*)(maskrow + sn*16 + quad*4);
      ushort4 p;
      p.x = f2bf((acc[sn][0][0] + bv) * (1.0f/512.0f) * mr.x);
      p.y = f2bf((acc[sn][0][1] + bv) * (1.0f/512.0f) * mr.y);
      p.z = f2bf((acc[sn][0][2] + bv) * (1.0f/512.0f) * mr.z);
      p.w = f2bf((acc[sn][0][3] + bv) * (1.0f/512.0f) * mr.w);
      *(ushort4*)(rowp + sn*16 + quad*4) = p;
    }
  }
}

// ---------------- sort + pool ----------------
// one wave per (b,c) row: 512 elems, 8/lane, full bitonic descending
__global__ void k_pool(const ushort_t* __restrict__ h4, const float* __restrict__ pw,
                       float* __restrict__ out)
{
  const int lane = threadIdx.x & 63;
  const int wave = threadIdx.x >> 6;
  const size_t r = (size_t)blockIdx.x*4 + wave;    // 0..131071
  const int b = (int)(r >> 7), c = (int)(r & 127);

  uint4 raw = *(const uint4*)(h4 + r*NPOS + lane*8);
  float v[8];
  {
    unsigned ww[4] = {raw.x, raw.y, raw.z, raw.w};
    #pragma unroll
    for (int i=0;i<4;i++){
      union {float f; unsigned u;} lo, hi;
      lo.u = ww[i] << 16;
      hi.u = ww[i] & 0xffff0000u;
      v[2*i] = lo.f; v[2*i+1] = hi.f;
    }
  }

  #pragma unroll
  for (int k=2; k<=512; k<<=1){
    #pragma unroll
    for (int j=k>>1; j>=8; j>>=1){            // cross-lane steps
      const int lm = j >> 3;
      const bool lower = (lane & lm) == 0;
      const bool desc  = ((lane*8) & k) == 0; // k>=16 here: r-bits irrelevant
      #pragma unroll
      for (int rr=0;rr<8;rr++){
        float o = __shfl_xor(v[rr], lm);
        v[rr] = (desc == lower) ? fmaxf(v[rr], o) : fminf(v[rr], o);
      }
    }
    #pragma unroll
    for (int j = ((k>>1) < 8 ? (k>>1) : 4); j>=1; j>>=1){   // in-lane steps
      #pragma unroll
      for (int rr=0;rr<8;rr++){
        if ((rr & j) == 0){
          const bool desc = (((lane*8 + rr) & k) == 0);
          float a = v[rr], b2 = v[rr|j];
          bool sw = desc ? (a < b2) : (a > b2);
          if (sw){ v[rr] = b2; v[rr|j] = a; }
        }
      }
    }
  }

  float s = 0.f;
  #pragma unroll
  for (int rr=0;rr<8;rr++){
    int e = lane*8 + rr;
    float pos = (float)e * (20.0f/511.0f);
    int idx = (int)pos; if (idx > 20) idx = 20;
    float frac = pos - (float)idx;
    int i2 = (idx+1 > 20) ? 20 : idx+1;
    float wl = pw[c*21 + idx], wr = pw[c*21 + i2];
    s += v[rr] * (wl + frac*(wr-wl));
  }
  #pragma unroll
  for (int off=32; off>=1; off>>=1) s += __shfl_xor(s, off);
  if (lane == 0) out[b*129 + c] = s;
}

// ---------------- size feature ----------------
__global__ void k_size(const float* __restrict__ mask, float* __restrict__ out){
  const int b = blockIdx.x, lane = threadIdx.x;
  float s = 0.f;
  #pragma unroll
  for (int i=0;i<8;i++) s += mask[(size_t)b*NPOS + i*64 + lane];
  #pragma unroll
  for (int off=32; off>=1; off>>=1) s += __shfl_xor(s, off);
  if (lane == 0) out[b*129 + 128] = s * (1.0f/128.0f);  // mean*4 = sum/512*4
}

extern "C" void kernel_launch(void* const* d_in, const int* in_sizes, int n_in,
                              void* d_out, int out_size, void* d_ws, size_t ws_size,
                              hipStream_t stream){
  const float* x    = (const float*)d_in[0];
  const float* mask = (const float*)d_in[1];
  const float* w1   = (const float*)d_in[2];
  const float* b1   = (const float*)d_in[3];
  const float* w2   = (const float*)d_in[4];
  const float* b2   = (const float*)d_in[5];
  const float* w3   = (const float*)d_in[6];
  const float* b3   = (const float*)d_in[7];
  const float* w4   = (const float*)d_in[8];
  const float* b4   = (const float*)d_in[9];
  const float* pw   = (const float*)d_in[10];
  float* out = (float*)d_out;

  // ws: h4 bf16 (1024*128*512 = 128MB) | w2b | w3b | w4b
  ushort_t* h4  = (ushort_t*)d_ws;
  ushort_t* w2b = h4 + (size_t)1024*CO*NPOS;
  ushort_t* w3b = w2b + 65536;
  ushort_t* w4b = w3b + 65536;

  k_prep <<<640,   256, 0, stream>>>(w2, w3, w4, w2b);
  k_fused<<<8192,  512, 0, stream>>>(x, mask, w1, b1, w2b, b2, w3b, b3, w4b, b4, h4);
  k_pool <<<32768, 256, 0, stream>>>(h4, pw, out);
  k_size <<<1024,  64,  0, stream>>>(mask, out);
}

// Round 4
// 559.590 us; speedup vs baseline: 2.7762x; 1.2741x over previous
//
#include <hip/hip_runtime.h>
#include <hip/hip_bf16.h>

typedef __bf16 bf16x8 __attribute__((ext_vector_type(8)));
typedef float f32x4 __attribute__((ext_vector_type(4)));
typedef unsigned short ushort_t;

#define NPOS 512
#define CIN  5
#define CO   128

static __device__ __forceinline__ unsigned short f2bf(float f){
  union { __hip_bfloat16 h; unsigned short u; } cv;
  cv.h = __float2bfloat16(f);
  return cv.u;
}

// packed u16 min/max (VOP3P) — one op handles two independent sort rows
static __device__ __forceinline__ unsigned pk_min_u16(unsigned a, unsigned b){
  unsigned d; asm("v_pk_min_u16 %0, %1, %2" : "=v"(d) : "v"(a), "v"(b)); return d;
}
static __device__ __forceinline__ unsigned pk_max_u16(unsigned a, unsigned b){
  unsigned d; asm("v_pk_max_u16 %0, %1, %2" : "=v"(d) : "v"(a), "v"(b)); return d;
}

// ---------------- weight fp32 -> bf16 prep ----------------
__global__ void k_prep(const float* __restrict__ w2, const float* __restrict__ w3,
                       const float* __restrict__ w4, ushort_t* __restrict__ o){
  int i = blockIdx.x*256 + threadIdx.x;   // grid covers 163840 exactly
  if (i < 65536)        o[i] = f2bf(w2[i]);
  else if (i < 131072)  o[i] = f2bf(w3[i-65536]);
  else                  o[i] = f2bf(w4[i-131072]);
}

// ---------------- fused conv1..conv4 ----------------
// Fragment-major LDS act layout: element (n,c) in 16B chunk
//   chunk(n,c) = (n>>4)*512 + (c>>5)*64 + ((c>>3)&3)*16 + (n&15), j = c&7
// A-read: chunk = sn*512 + ks*64 + lane -> lane-sequential b128, conflict-free.
// W register-prefetched whole-layer (wr[8][2] = 64 VGPR), next layer's W loads
// issued behind the current epilogue+barrier. 512 threads, ~4 waves/SIMD.

template<int NSD>
static __device__ __forceinline__ void load_w(bf16x8 (&wr)[8][2],
    const ushort_t* __restrict__ Wb, int wave, int lane){
  const int m = lane & 15, quad = lane >> 4;
  const int d0 = wave * (NSD*16);
  #pragma unroll
  for (int ks=0; ks<8; ks++)
    #pragma unroll
    for (int sd=0; sd<NSD; sd++)
      wr[ks][sd] = *(const bf16x8*)(Wb + (d0 + sd*16 + m)*256 + ks*32 + quad*8);
}

template<int NSD>
static __device__ __forceinline__ void mfma_phase(const bf16x8 (&wr)[8][2],
    const ushort_t* __restrict__ src, f32x4 (&acc)[4][2], int lane){
  #pragma unroll
  for (int sn=0;sn<4;sn++)
    #pragma unroll
    for (int sd=0;sd<NSD;sd++)
      acc[sn][sd] = (f32x4){0.f,0.f,0.f,0.f};
  bf16x8 a[4], an[4];
  #pragma unroll
  for (int sn=0;sn<4;sn++)
    a[sn] = *(const bf16x8*)(src + ((sn*512 + lane) << 3));
  #pragma unroll
  for (int ks=0; ks<8; ks++){
    if (ks < 7){                                  // prefetch next ks A-frags
      #pragma unroll
      for (int sn=0;sn<4;sn++)
        an[sn] = *(const bf16x8*)(src + ((sn*512 + (ks+1)*64 + lane) << 3));
    }
    #pragma unroll
    for (int sd=0;sd<NSD;sd++)
      #pragma unroll
      for (int sn=0;sn<4;sn++)
        acc[sn][sd] = __builtin_amdgcn_mfma_f32_16x16x32_bf16(a[sn], wr[ks][sd], acc[sn][sd], 0,0,0);
    #pragma unroll
    for (int sn=0;sn<4;sn++) a[sn] = an[sn];
  }
}

static __device__ __forceinline__ void epilogue_relu(const f32x4 (&acc)[4][2],
    const float* __restrict__ bias, ushort_t* __restrict__ dst, int wave, int lane){
  const int m = lane & 15, quad = lane >> 4;
  const int d0 = wave * 32;
  #pragma unroll
  for (int sd=0;sd<2;sd++){
    int d = d0 + sd*16 + m;
    float bv = bias[d];
    int colbase = (d>>5)*64 + ((d>>3)&3)*16;
    int j = d & 7;
    #pragma unroll
    for (int sn=0;sn<4;sn++){
      #pragma unroll
      for (int rg=0;rg<4;rg++){
        float v = fmaxf(acc[sn][sd][rg] + bv, 0.f);
        dst[((sn*512 + colbase + quad*4 + rg) << 3) + j] = f2bf(v);
      }
    }
  }
}

__global__ __launch_bounds__(512,4) void k_fused(
  const float* __restrict__ x, const float* __restrict__ mask,
  const float* __restrict__ w1, const float* __restrict__ b1,
  const ushort_t* __restrict__ w2b, const float* __restrict__ b2,
  const ushort_t* __restrict__ w3b, const float* __restrict__ b3,
  const ushort_t* __restrict__ w4b, const float* __restrict__ b4,
  ushort_t* __restrict__ h4)
{
  __shared__ __align__(16) ushort_t A [64*256];
  __shared__ __align__(16) ushort_t Bf[64*256];
  __shared__ __align__(16) float xs[CIN][64];
  const int t    = threadIdx.x;
  const int bid  = blockIdx.x;
  const int b    = bid >> 3;
  const int n0   = (bid & 7) << 6;
  const int wave = t >> 6, lane = t & 63;

  bf16x8 wr[8][2];
  f32x4  acc[4][2];

  if (t < 80){
    int c = t >> 4, ch = t & 15;
    *(float4*)&xs[c][ch*4] = *(const float4*)(x + ((size_t)b*CIN + c)*NPOS + n0 + ch*4);
  }

  // layer-1: thread owns c-octet oct=(t>>4)&31 over n = i*16 + (t&15)
  {
    const int oct = (t >> 4) & 31, mn = t & 15;
    float wv[40];
    #pragma unroll
    for (int q=0;q<10;q++)
      *(float4*)&wv[q*4] = *(const float4*)(w1 + oct*40 + q*4);
    float bs1[8];
    *(float4*)&bs1[0] = *(const float4*)(b1 + oct*8);
    *(float4*)&bs1[4] = *(const float4*)(b1 + oct*8 + 4);

    __syncthreads();                       // xs ready

    #pragma unroll
    for (int i=0;i<4;i++){
      int n = i*16 + mn;
      float acc1[8];
      #pragma unroll
      for (int j=0;j<8;j++) acc1[j] = bs1[j];
      #pragma unroll
      for (int c=0;c<CIN;c++){
        float xv = xs[c][n];
        #pragma unroll
        for (int j=0;j<8;j++) acc1[j] = fmaf(wv[j*CIN + c], xv, acc1[j]);
      }
      unsigned u[4];
      #pragma unroll
      for (int j=0;j<4;j++){
        unsigned lo = f2bf(fmaxf(acc1[2*j  ],0.f));
        unsigned hi = f2bf(fmaxf(acc1[2*j+1],0.f));
        u[j] = lo | (hi<<16);
      }
      *(uint4*)&A[(i*512 + t) << 3] = make_uint4(u[0],u[1],u[2],u[3]);
    }
  }

  load_w<2>(wr, w2b, wave, lane);          // W2 in flight across barrier
  __syncthreads();

  mfma_phase<2>(wr, A, acc, lane);         // layer 2
  load_w<2>(wr, w3b, wave, lane);          // W3 in flight during epilogue
  epilogue_relu(acc, b2, Bf, wave, lane);
  __syncthreads();

  mfma_phase<2>(wr, Bf, acc, lane);        // layer 3
  load_w<1>(wr, w4b, wave, lane);          // W4 in flight
  epilogue_relu(acc, b3, A, wave, lane);
  __syncthreads();

  mfma_phase<1>(wr, A, acc, lane);         // layer 4 (wave owns 16 d)
  {
    const int m = lane & 15, quad = lane >> 4;
    const int d = wave*16 + m;
    const float bv = b4[d];
    const float* maskrow = mask + (size_t)b*NPOS + n0;
    ushort_t* rowp = h4 + ((size_t)b*CO + d)*NPOS + n0;
    #pragma unroll
    for (int sn=0;sn<4;sn++){
      float4 mr = *(const float4*)(maskrow + sn*16 + quad*4);
      ushort4 p;
      p.x = f2bf((acc[sn][0][0] + bv) * (1.0f/512.0f) * mr.x);
      p.y = f2bf((acc[sn][0][1] + bv) * (1.0f/512.0f) * mr.y);
      p.z = f2bf((acc[sn][0][2] + bv) * (1.0f/512.0f) * mr.z);
      p.w = f2bf((acc[sn][0][3] + bv) * (1.0f/512.0f) * mr.w);
      *(ushort4*)(rowp + sn*16 + quad*4) = p;
    }
  }
}

// ---------------- sort + pool ----------------
// Packed bitonic: TWO rows per wave, row0 in low u16 halves / row1 in high,
// 8 regs x (2x u16). Element index i = lane*8 + reg. Every shfl moves both
// rows (84 ds-ops/row vs 168 in R3); compares are v_pk_min/max_u16.
// bf16 -> order-preserving u16 key: key = u ^ (0x8000 | 0x7FFF*sign).
__global__ void k_pool(const ushort_t* __restrict__ h4, const float* __restrict__ pw,
                       float* __restrict__ out)
{
  const int lane = threadIdx.x & 63;
  const int wave = threadIdx.x >> 6;
  const size_t r0 = (size_t)blockIdx.x*8 + wave*2;   // rows r0, r0+1
  const int b0 = (int)(r0 >> 7), c0 = (int)(r0 & 127);
  const int b1_ = (int)((r0+1) >> 7), c1 = (int)((r0+1) & 127);

  uint4 ra = *(const uint4*)(h4 + r0*NPOS     + lane*8);
  uint4 rb = *(const uint4*)(h4 + (r0+1)*NPOS + lane*8);

  unsigned v[8];
  v[0] = (ra.x & 0xFFFFu) | (rb.x << 16);
  v[1] = (ra.x >> 16)     | (rb.x & 0xFFFF0000u);
  v[2] = (ra.y & 0xFFFFu) | (rb.y << 16);
  v[3] = (ra.y >> 16)     | (rb.y & 0xFFFF0000u);
  v[4] = (ra.z & 0xFFFFu) | (rb.z << 16);
  v[5] = (ra.z >> 16)     | (rb.z & 0xFFFF0000u);
  v[6] = (ra.w & 0xFFFFu) | (rb.w << 16);
  v[7] = (ra.w >> 16)     | (rb.w & 0xFFFF0000u);

  // bf16 -> sortable key (both halves at once)
  #pragma unroll
  for (int i=0;i<8;i++){
    unsigned sb = (v[i] >> 15) & 0x00010001u;
    v[i] = v[i] ^ 0x80008000u ^ (sb * 0x7FFFu);
  }

  // compile-time-direction compare-exchange on reg pair (lo index a)
  #define CE_UP(a,b)   { unsigned mn=pk_min_u16(v[a],v[b]), mx=pk_max_u16(v[a],v[b]); v[a]=mn; v[b]=mx; }
  #define CE_DN(a,b)   { unsigned mn=pk_min_u16(v[a],v[b]), mx=pk_max_u16(v[a],v[b]); v[a]=mx; v[b]=mn; }
  // runtime direction (up bool): ascending iff up
  #define CE_RT(a,b,up){ unsigned mn=pk_min_u16(v[a],v[b]), mx=pk_max_u16(v[a],v[b]); v[a]=(up)?mn:mx; v[b]=(up)?mx:mn; }

  // k=2 (j=1):
  CE_UP(0,1); CE_DN(2,3); CE_UP(4,5); CE_DN(6,7);
  // k=4:
  CE_UP(0,2); CE_UP(1,3); CE_DN(4,6); CE_DN(5,7);          // j=2
  CE_UP(0,1); CE_UP(2,3); CE_DN(4,5); CE_DN(6,7);          // j=1
  // k=8 (dir lane-dependent):
  {
    const bool up = (lane & 1) == 0;
    CE_RT(0,4,up); CE_RT(1,5,up); CE_RT(2,6,up); CE_RT(3,7,up);   // j=4
    CE_RT(0,2,up); CE_RT(1,3,up); CE_RT(4,6,up); CE_RT(5,7,up);   // j=2
    CE_RT(0,1,up); CE_RT(2,3,up); CE_RT(4,5,up); CE_RT(6,7,up);   // j=1
  }
  // k = 16 .. 512: cross-lane merges then in-lane cleanup
  #pragma unroll
  for (int k=16; k<=512; k<<=1){
    const bool up = (lane & (k>>3)) == 0;
    #pragma unroll
    for (int lm = (k>>4); lm >= 1; lm >>= 1){                      // j = lm*8
      const bool lower = (lane & lm) == 0;
      const bool keepmin = (up == lower);
      #pragma unroll
      for (int i=0;i<8;i++){
        unsigned o = __shfl_xor((int)v[i], lm);
        unsigned mn = pk_min_u16(v[i], (unsigned)o);
        unsigned mx = pk_max_u16(v[i], (unsigned)o);
        v[i] = keepmin ? mn : mx;
      }
    }
    CE_RT(0,4,up); CE_RT(1,5,up); CE_RT(2,6,up); CE_RT(3,7,up);   // j=4
    CE_RT(0,2,up); CE_RT(1,3,up); CE_RT(4,6,up); CE_RT(5,7,up);   // j=2
    CE_RT(0,1,up); CE_RT(2,3,up); CE_RT(4,5,up); CE_RT(6,7,up);   // j=1
  }
  #undef CE_UP
  #undef CE_DN
  #undef CE_RT

  // key -> bf16 bits (both halves)
  #pragma unroll
  for (int i=0;i<8;i++){
    unsigned sb = ((~v[i]) >> 15) & 0x00010001u;
    v[i] = v[i] ^ 0x80008000u ^ (sb * 0x7FFFu);
  }

  // ascending position i = lane*8 + reg -> descending rank r = 511 - i
  float s0 = 0.f, s1 = 0.f;
  #pragma unroll
  for (int i=0;i<8;i++){
    int rk = 511 - (lane*8 + i);
    float pos = (float)rk * (20.0f/511.0f);
    int idx = (int)pos; if (idx > 20) idx = 20;
    float frac = pos - (float)idx;
    int i2 = (idx+1 > 20) ? 20 : idx+1;
    float wl0 = pw[c0*21 + idx], wr0 = pw[c0*21 + i2];
    float wl1 = pw[c1*21 + idx], wr1 = pw[c1*21 + i2];
    union {unsigned u; float f;} lo, hi;
    lo.u = v[i] << 16;
    hi.u = v[i] & 0xFFFF0000u;
    s0 += lo.f * (wl0 + frac*(wr0-wl0));
    s1 += hi.f * (wl1 + frac*(wr1-wl1));
  }
  #pragma unroll
  for (int off=32; off>=1; off>>=1){
    s0 += __shfl_xor(s0, off);
    s1 += __shfl_xor(s1, off);
  }
  if (lane == 0){
    out[b0*129 + c0]  = s0;
    out[b1_*129 + c1] = s1;
  }
}

// ---------------- size feature ----------------
__global__ void k_size(const float* __restrict__ mask, float* __restrict__ out){
  const int b = blockIdx.x, lane = threadIdx.x;
  float s = 0.f;
  #pragma unroll
  for (int i=0;i<8;i++) s += mask[(size_t)b*NPOS + i*64 + lane];
  #pragma unroll
  for (int off=32; off>=1; off>>=1) s += __shfl_xor(s, off);
  if (lane == 0) out[b*129 + 128] = s * (1.0f/128.0f);  // mean*4 = sum/512*4
}

extern "C" void kernel_launch(void* const* d_in, const int* in_sizes, int n_in,
                              void* d_out, int out_size, void* d_ws, size_t ws_size,
                              hipStream_t stream){
  const float* x    = (const float*)d_in[0];
  const float* mask = (const float*)d_in[1];
  const float* w1   = (const float*)d_in[2];
  const float* b1   = (const float*)d_in[3];
  const float* w2   = (const float*)d_in[4];
  const float* b2   = (const float*)d_in[5];
  const float* w3   = (const float*)d_in[6];
  const float* b3   = (const float*)d_in[7];
  const float* w4   = (const float*)d_in[8];
  const float* b4   = (const float*)d_in[9];
  const float* pw   = (const float*)d_in[10];
  float* out = (float*)d_out;

  // ws: h4 bf16 (1024*128*512 = 128MB) | w2b | w3b | w4b
  ushort_t* h4  = (ushort_t*)d_ws;
  ushort_t* w2b = h4 + (size_t)1024*CO*NPOS;
  ushort_t* w3b = w2b + 65536;
  ushort_t* w4b = w3b + 65536;

  k_prep <<<640,   256, 0, stream>>>(w2, w3, w4, w2b);
  k_fused<<<8192,  512, 0, stream>>>(x, mask, w1, b1, w2b, b2, w3b, b3, w4b, b4, h4);
  k_pool <<<16384, 256, 0, stream>>>(h4, pw, out);
  k_size <<<1024,  64,  0, stream>>>(mask, out);
}

// Round 5
// 550.716 us; speedup vs baseline: 2.8210x; 1.0161x over previous
//
#include <hip/hip_runtime.h>
#include <hip/hip_bf16.h>

typedef __bf16 bf16x8 __attribute__((ext_vector_type(8)));
typedef float f32x4 __attribute__((ext_vector_type(4)));
typedef unsigned short ushort_t;

#define NPOS 512
#define CIN  5
#define CO   128

static __device__ __forceinline__ unsigned short f2bf(float f){
  union { __hip_bfloat16 h; unsigned short u; } cv;
  cv.h = __float2bfloat16(f);
  return cv.u;
}

// packed f32->bf16x2 (v_cvt_pk_bf16_f32 on gfx950) — RNE, 1 op per 2 values
static __device__ __forceinline__ ushort2 cvtpk(float a, float b){
  union { __hip_bfloat162 h2; ushort2 u; } cv;
  cv.h2 = __float22bfloat162_rn(make_float2(a, b));
  return cv.u;
}
static __device__ __forceinline__ unsigned cvtpk_u32(float a, float b){
  union { __hip_bfloat162 h2; unsigned u; } cv;
  cv.h2 = __float22bfloat162_rn(make_float2(a, b));
  return cv.u;
}

// packed u16 min/max (VOP3P) — one op handles two independent sort rows
static __device__ __forceinline__ unsigned pk_min_u16(unsigned a, unsigned b){
  unsigned d; asm("v_pk_min_u16 %0, %1, %2" : "=v"(d) : "v"(a), "v"(b)); return d;
}
static __device__ __forceinline__ unsigned pk_max_u16(unsigned a, unsigned b){
  unsigned d; asm("v_pk_max_u16 %0, %1, %2" : "=v"(d) : "v"(a), "v"(b)); return d;
}

// ---------------- weight fp32 -> bf16 prep ----------------
__global__ void k_prep(const float* __restrict__ w2, const float* __restrict__ w3,
                       const float* __restrict__ w4, ushort_t* __restrict__ o){
  int i = blockIdx.x*256 + threadIdx.x;   // grid covers 163840 exactly
  if (i < 65536)        o[i] = f2bf(w2[i]);
  else if (i < 131072)  o[i] = f2bf(w3[i-65536]);
  else                  o[i] = f2bf(w4[i-131072]);
}

// ---------------- fused conv1..conv4 ----------------
// Single in-place activation buffer Act (fragment-major chunks):
//   element (n,c) in 16B chunk: chunk(n,c) = (n>>4)*512 + (c>>5)*64 + ((c>>3)&3)*16 + (n&15)
//   A-read for (sn,ks): chunk = sn*512 + ks*64 + lane -> lane-sequential b128, conflict-free.
// Phase: read Act -> acc (regs) -> barrier -> epilogue writes Act in place.
// W streamed from L2 with rolling 3-slot register prefetch (wr[3][2] = 24 VGPR,
// distance 2 ks). Total regs ~63 VGPR + 16 AGPR -> 6 waves/SIMD, 3 blocks/CU
// (R4 was register-capped at 4 waves/SIMD with whole-layer wr[8][2]=64).

template<int NSD>
static __device__ __forceinline__ void preload_w(bf16x8 (&wr)[3][2],
    const ushort_t* __restrict__ Wb, int slot, int ks, int wave, int lane){
  const int m = lane & 15, quad = lane >> 4;
  const int d0 = wave * (NSD*16);
  #pragma unroll
  for (int sd=0; sd<NSD; sd++)
    wr[slot][sd] = *(const bf16x8*)(Wb + (d0 + sd*16 + m)*256 + ks*32 + quad*8);
}

template<int NSD>
static __device__ __forceinline__ void mfma_stream(bf16x8 (&wr)[3][2],
    const ushort_t* __restrict__ Wb, const ushort_t* __restrict__ src,
    f32x4 (&acc)[4][NSD], int wave, int lane){
  #pragma unroll
  for (int sn=0;sn<4;sn++)
    #pragma unroll
    for (int sd=0;sd<NSD;sd++)
      acc[sn][sd] = (f32x4){0.f,0.f,0.f,0.f};
  #pragma unroll
  for (int ks=0; ks<8; ks++){
    if (ks < 6) preload_w<NSD>(wr, Wb, (ks+2)%3, ks+2, wave, lane);
    bf16x8 a[4];
    #pragma unroll
    for (int sn=0;sn<4;sn++)
      a[sn] = *(const bf16x8*)(src + ((sn*512 + ks*64 + lane) << 3));
    #pragma unroll
    for (int sd=0;sd<NSD;sd++)
      #pragma unroll
      for (int sn=0;sn<4;sn++)
        acc[sn][sd] = __builtin_amdgcn_mfma_f32_16x16x32_bf16(a[sn], wr[ks%3][sd], acc[sn][sd], 0,0,0);
  }
}

// layers 2/3: +bias, relu, write back into fragment-major layout (in-place)
static __device__ __forceinline__ void epilogue_relu(const f32x4 (&acc)[4][2],
    const float* __restrict__ bias, ushort_t* __restrict__ dst, int wave, int lane){
  const int m = lane & 15, quad = lane >> 4;
  const int d0 = wave * 32;
  #pragma unroll
  for (int sd=0;sd<2;sd++){
    int d = d0 + sd*16 + m;
    float bv = bias[d];
    int colbase = (d>>5)*64 + ((d>>3)&3)*16;
    int j = d & 7;
    #pragma unroll
    for (int sn=0;sn<4;sn++){
      float v0 = fmaxf(acc[sn][sd][0] + bv, 0.f);
      float v1 = fmaxf(acc[sn][sd][1] + bv, 0.f);
      float v2 = fmaxf(acc[sn][sd][2] + bv, 0.f);
      float v3 = fmaxf(acc[sn][sd][3] + bv, 0.f);
      ushort2 p01 = cvtpk(v0, v1);
      ushort2 p23 = cvtpk(v2, v3);
      int base = (sn*512 + colbase + quad*4) << 3;
      dst[base +  0 + j] = p01.x;
      dst[base +  8 + j] = p01.y;
      dst[base + 16 + j] = p23.x;
      dst[base + 24 + j] = p23.y;
    }
  }
}

__global__ __launch_bounds__(512,6) void k_fused(
  const float* __restrict__ x, const float* __restrict__ mask,
  const float* __restrict__ w1, const float* __restrict__ b1,
  const ushort_t* __restrict__ w2b, const float* __restrict__ b2,
  const ushort_t* __restrict__ w3b, const float* __restrict__ b3,
  const ushort_t* __restrict__ w4b, const float* __restrict__ b4,
  ushort_t* __restrict__ h4)
{
  __shared__ __align__(16) ushort_t Act[64*256];   // 32 KB, in-place across layers
  __shared__ __align__(16) float xs[CIN][64];
  const int t    = threadIdx.x;
  const int bid  = blockIdx.x;
  const int b    = bid >> 3;
  const int n0   = (bid & 7) << 6;
  const int wave = t >> 6, lane = t & 63;

  bf16x8 wr[3][2];

  if (t < 80){
    int c = t >> 4, ch = t & 15;
    *(float4*)&xs[c][ch*4] = *(const float4*)(x + ((size_t)b*CIN + c)*NPOS + n0 + ch*4);
  }

  // layer-1: thread owns c-octet oct=(t>>4)&31 over n = i*16 + (t&15)
  {
    const int oct = (t >> 4) & 31, mn = t & 15;
    float wv[40];
    #pragma unroll
    for (int q=0;q<10;q++)
      *(float4*)&wv[q*4] = *(const float4*)(w1 + oct*40 + q*4);
    float bs1[8];
    *(float4*)&bs1[0] = *(const float4*)(b1 + oct*8);
    *(float4*)&bs1[4] = *(const float4*)(b1 + oct*8 + 4);

    __syncthreads();                       // xs ready

    #pragma unroll
    for (int i=0;i<4;i++){
      int n = i*16 + mn;
      float acc1[8];
      #pragma unroll
      for (int j=0;j<8;j++) acc1[j] = bs1[j];
      #pragma unroll
      for (int c=0;c<CIN;c++){
        float xv = xs[c][n];
        #pragma unroll
        for (int j=0;j<8;j++) acc1[j] = fmaf(wv[j*CIN + c], xv, acc1[j]);
      }
      unsigned u[4];
      #pragma unroll
      for (int j=0;j<4;j++)
        u[j] = cvtpk_u32(fmaxf(acc1[2*j],0.f), fmaxf(acc1[2*j+1],0.f));
      *(uint4*)&Act[(i*512 + t) << 3] = make_uint4(u[0],u[1],u[2],u[3]);
    }
  }

  preload_w<2>(wr, w2b, 0, 0, wave, lane);   // W2 ks=0,1 in flight across barrier
  preload_w<2>(wr, w2b, 1, 1, wave, lane);
  __syncthreads();                           // (1) Act = h1 complete

  {
    f32x4 acc[4][2];
    mfma_stream<2>(wr, w2b, Act, acc, wave, lane);   // layer 2
    preload_w<2>(wr, w3b, 0, 0, wave, lane);         // W3 head in flight
    preload_w<2>(wr, w3b, 1, 1, wave, lane);
    __syncthreads();                         // (2) all h1 reads done
    epilogue_relu(acc, b2, Act, wave, lane);
  }
  __syncthreads();                           // (3) Act = h2 complete

  {
    f32x4 acc[4][2];
    mfma_stream<2>(wr, w3b, Act, acc, wave, lane);   // layer 3
    preload_w<1>(wr, w4b, 0, 0, wave, lane);         // W4 head in flight
    preload_w<1>(wr, w4b, 1, 1, wave, lane);
    __syncthreads();                         // (4) all h2 reads done
    epilogue_relu(acc, b3, Act, wave, lane);
  }
  __syncthreads();                           // (5) Act = h3 complete

  {
    f32x4 acc[4][1];
    mfma_stream<1>(wr, w4b, Act, acc, wave, lane);   // layer 4 (wave owns 16 d)
    const int m = lane & 15, quad = lane >> 4;
    const int d = wave*16 + m;
    const float bv = b4[d];
    const float* maskrow = mask + (size_t)b*NPOS + n0;
    ushort_t* rowp = h4 + ((size_t)b*CO + d)*NPOS + n0;
    #pragma unroll
    for (int sn=0;sn<4;sn++){
      float4 mr = *(const float4*)(maskrow + sn*16 + quad*4);
      ushort2 p01 = cvtpk((acc[sn][0][0] + bv) * (1.0f/512.0f) * mr.x,
                          (acc[sn][0][1] + bv) * (1.0f/512.0f) * mr.y);
      ushort2 p23 = cvtpk((acc[sn][0][2] + bv) * (1.0f/512.0f) * mr.z,
                          (acc[sn][0][3] + bv) * (1.0f/512.0f) * mr.w);
      ushort4 p; p.x = p01.x; p.y = p01.y; p.z = p23.x; p.w = p23.y;
      *(ushort4*)(rowp + sn*16 + quad*4) = p;
    }
  }
}

// ---------------- sort + pool ----------------
// Packed bitonic: TWO rows per wave, row0 in low u16 halves / row1 in high,
// 8 regs x (2x u16). Element index i = lane*8 + reg. Every shfl moves both
// rows; compares are v_pk_min/max_u16.
// bf16 -> order-preserving u16 key: key = u ^ (0x8000 | 0x7FFF*sign).
__global__ void k_pool(const ushort_t* __restrict__ h4, const float* __restrict__ pw,
                       float* __restrict__ out)
{
  const int lane = threadIdx.x & 63;
  const int wave = threadIdx.x >> 6;
  const size_t r0 = (size_t)blockIdx.x*8 + wave*2;   // rows r0, r0+1
  const int b0 = (int)(r0 >> 7), c0 = (int)(r0 & 127);
  const int b1_ = (int)((r0+1) >> 7), c1 = (int)((r0+1) & 127);

  uint4 ra = *(const uint4*)(h4 + r0*NPOS     + lane*8);
  uint4 rb = *(const uint4*)(h4 + (r0+1)*NPOS + lane*8);

  unsigned v[8];
  v[0] = (ra.x & 0xFFFFu) | (rb.x << 16);
  v[1] = (ra.x >> 16)     | (rb.x & 0xFFFF0000u);
  v[2] = (ra.y & 0xFFFFu) | (rb.y << 16);
  v[3] = (ra.y >> 16)     | (rb.y & 0xFFFF0000u);
  v[4] = (ra.z & 0xFFFFu) | (rb.z << 16);
  v[5] = (ra.z >> 16)     | (rb.z & 0xFFFF0000u);
  v[6] = (ra.w & 0xFFFFu) | (rb.w << 16);
  v[7] = (ra.w >> 16)     | (rb.w & 0xFFFF0000u);

  // bf16 -> sortable key (both halves at once)
  #pragma unroll
  for (int i=0;i<8;i++){
    unsigned sb = (v[i] >> 15) & 0x00010001u;
    v[i] = v[i] ^ 0x80008000u ^ (sb * 0x7FFFu);
  }

  #define CE_UP(a,b)   { unsigned mn=pk_min_u16(v[a],v[b]), mx=pk_max_u16(v[a],v[b]); v[a]=mn; v[b]=mx; }
  #define CE_DN(a,b)   { unsigned mn=pk_min_u16(v[a],v[b]), mx=pk_max_u16(v[a],v[b]); v[a]=mx; v[b]=mn; }
  #define CE_RT(a,b,up){ unsigned mn=pk_min_u16(v[a],v[b]), mx=pk_max_u16(v[a],v[b]); v[a]=(up)?mn:mx; v[b]=(up)?mx:mn; }

  // k=2 (j=1):
  CE_UP(0,1); CE_DN(2,3); CE_UP(4,5); CE_DN(6,7);
  // k=4:
  CE_UP(0,2); CE_UP(1,3); CE_DN(4,6); CE_DN(5,7);          // j=2
  CE_UP(0,1); CE_UP(2,3); CE_DN(4,5); CE_DN(6,7);          // j=1
  // k=8 (dir lane-dependent):
  {
    const bool up = (lane & 1) == 0;
    CE_RT(0,4,up); CE_RT(1,5,up); CE_RT(2,6,up); CE_RT(3,7,up);   // j=4
    CE_RT(0,2,up); CE_RT(1,3,up); CE_RT(4,6,up); CE_RT(5,7,up);   // j=2
    CE_RT(0,1,up); CE_RT(2,3,up); CE_RT(4,5,up); CE_RT(6,7,up);   // j=1
  }
  // k = 16 .. 512: cross-lane merges then in-lane cleanup
  #pragma unroll
  for (int k=16; k<=512; k<<=1){
    const bool up = (lane & (k>>3)) == 0;
    #pragma unroll
    for (int lm = (k>>4); lm >= 1; lm >>= 1){                      // j = lm*8
      const bool lower = (lane & lm) == 0;
      const bool keepmin = (up == lower);
      #pragma unroll
      for (int i=0;i<8;i++){
        unsigned o = __shfl_xor((int)v[i], lm);
        unsigned mn = pk_min_u16(v[i], (unsigned)o);
        unsigned mx = pk_max_u16(v[i], (unsigned)o);
        v[i] = keepmin ? mn : mx;
      }
    }
    CE_RT(0,4,up); CE_RT(1,5,up); CE_RT(2,6,up); CE_RT(3,7,up);   // j=4
    CE_RT(0,2,up); CE_RT(1,3,up); CE_RT(4,6,up); CE_RT(5,7,up);   // j=2
    CE_RT(0,1,up); CE_RT(2,3,up); CE_RT(4,5,up); CE_RT(6,7,up);   // j=1
  }
  #undef CE_UP
  #undef CE_DN
  #undef CE_RT

  // key -> bf16 bits (both halves)
  #pragma unroll
  for (int i=0;i<8;i++){
    unsigned sb = ((~v[i]) >> 15) & 0x00010001u;
    v[i] = v[i] ^ 0x80008000u ^ (sb * 0x7FFFu);
  }

  // ascending position i = lane*8 + reg -> descending rank r = 511 - i
  float s0 = 0.f, s1 = 0.f;
  #pragma unroll
  for (int i=0;i<8;i++){
    int rk = 511 - (lane*8 + i);
    float pos = (float)rk * (20.0f/511.0f);
    int idx = (int)pos; if (idx > 20) idx = 20;
    float frac = pos - (float)idx;
    int i2 = (idx+1 > 20) ? 20 : idx+1;
    float wl0 = pw[c0*21 + idx], wr0 = pw[c0*21 + i2];
    float wl1 = pw[c1*21 + idx], wr1 = pw[c1*21 + i2];
    union {unsigned u; float f;} lo, hi;
    lo.u = v[i] << 16;
    hi.u = v[i] & 0xFFFF0000u;
    s0 += lo.f * (wl0 + frac*(wr0-wl0));
    s1 += hi.f * (wl1 + frac*(wr1-wl1));
  }
  #pragma unroll
  for (int off=32; off>=1; off>>=1){
    s0 += __shfl_xor(s0, off);
    s1 += __shfl_xor(s1, off);
  }
  if (lane == 0){
    out[b0*129 + c0]  = s0;
    out[b1_*129 + c1] = s1;
  }
}

// ---------------- size feature ----------------
__global__ void k_size(const float* __restrict__ mask, float* __restrict__ out){
  const int b = blockIdx.x, lane = threadIdx.x;
  float s = 0.f;
  #pragma unroll
  for (int i=0;i<8;i++) s += mask[(size_t)b*NPOS + i*64 + lane];
  #pragma unroll
  for (int off=32; off>=1; off>>=1) s += __shfl_xor(s, off);
  if (lane == 0) out[b*129 + 128] = s * (1.0f/128.0f);  // mean*4 = sum/512*4
}

extern "C" void kernel_launch(void* const* d_in, const int* in_sizes, int n_in,
                              void* d_out, int out_size, void* d_ws, size_t ws_size,
                              hipStream_t stream){
  const float* x    = (const float*)d_in[0];
  const float* mask = (const float*)d_in[1];
  const float* w1   = (const float*)d_in[2];
  const float* b1   = (const float*)d_in[3];
  const float* w2   = (const float*)d_in[4];
  const float* b2   = (const float*)d_in[5];
  const float* w3   = (const float*)d_in[6];
  const float* b3   = (const float*)d_in[7];
  const float* w4   = (const float*)d_in[8];
  const float* b4   = (const float*)d_in[9];
  const float* pw   = (const float*)d_in[10];
  float* out = (float*)d_out;

  // ws: h4 bf16 (1024*128*512 = 128MB) | w2b | w3b | w4b
  ushort_t* h4  = (ushort_t*)d_ws;
  ushort_t* w2b = h4 + (size_t)1024*CO*NPOS;
  ushort_t* w3b = w2b + 65536;
  ushort_t* w4b = w3b + 65536;

  k_prep <<<640,   256, 0, stream>>>(w2, w3, w4, w2b);
  k_fused<<<8192,  512, 0, stream>>>(x, mask, w1, b1, w2b, b2, w3b, b3, w4b, b4, h4);
  k_pool <<<16384, 256, 0, stream>>>(h4, pw, out);
  k_size <<<1024,  64,  0, stream>>>(mask, out);
}

// Round 6
// 539.627 us; speedup vs baseline: 2.8790x; 1.0205x over previous
//
#include <hip/hip_runtime.h>
#include <hip/hip_bf16.h>

typedef __bf16 bf16x8 __attribute__((ext_vector_type(8)));
typedef float f32x4 __attribute__((ext_vector_type(4)));
typedef unsigned short ushort_t;

#define NPOS 512
#define CIN  5
#define CO   128

static __device__ __forceinline__ unsigned short f2bf(float f){
  union { __hip_bfloat16 h; unsigned short u; } cv;
  cv.h = __float2bfloat16(f);
  return cv.u;
}

// packed f32->bf16x2 (v_cvt_pk_bf16_f32 on gfx950) — RNE, 1 op per 2 values
static __device__ __forceinline__ ushort2 cvtpk(float a, float b){
  union { __hip_bfloat162 h2; ushort2 u; } cv;
  cv.h2 = __float22bfloat162_rn(make_float2(a, b));
  return cv.u;
}
static __device__ __forceinline__ unsigned cvtpk_u32(float a, float b){
  union { __hip_bfloat162 h2; unsigned u; } cv;
  cv.h2 = __float22bfloat162_rn(make_float2(a, b));
  return cv.u;
}

// packed u16 min/max (VOP3P) — one op handles two independent sort rows
static __device__ __forceinline__ unsigned pk_min_u16(unsigned a, unsigned b){
  unsigned d; asm("v_pk_min_u16 %0, %1, %2" : "=v"(d) : "v"(a), "v"(b)); return d;
}
static __device__ __forceinline__ unsigned pk_max_u16(unsigned a, unsigned b){
  unsigned d; asm("v_pk_max_u16 %0, %1, %2" : "=v"(d) : "v"(a), "v"(b)); return d;
}

// ---------------- weight fp32 -> bf16 prep ----------------
// o = [w2b 65536 | w3b 65536 | w4b 32768 | w1b 8192 (256 d x 32 k, k>=5 zero)]
__global__ void k_prep(const float* __restrict__ w1, const float* __restrict__ w2,
                       const float* __restrict__ w3, const float* __restrict__ w4,
                       ushort_t* __restrict__ o){
  int i = blockIdx.x*256 + threadIdx.x;   // grid covers 172032 exactly
  if (i < 65536)        o[i] = f2bf(w2[i]);
  else if (i < 131072)  o[i] = f2bf(w3[i-65536]);
  else if (i < 163840)  o[i] = f2bf(w4[i-131072]);
  else {
    int j = i - 163840;                   // 0..8191
    int d = j >> 5, k = j & 31;
    o[i] = (k < CIN) ? f2bf(w1[d*CIN + k]) : (ushort_t)0;
  }
}

// ---------------- fused conv1..conv4 (all-MFMA) ----------------
// 256-thread blocks (4 waves); block owns (batch b, 64-n tile); wave owns a
// 64-wide d-slice (32 for layer 4). Act: single in-place 32 KB buffer,
// fragment-major chunks: element (n,c) in 16B chunk
//   chunk(n,c) = (n>>4)*512 + (c>>5)*64 + ((c>>3)&3)*16 + (n&15), j-slot = c&7
// A-read (sn,ks): chunk = sn*512 + ks*64 + lane -> lane-sequential b128.
// d64/wave halves LDS A-traffic vs R5 (each wave reads Act once per layer,
// 4 readers instead of 8). Layer 1 runs as one MFMA ks-step with K=32
// zero-padded w1b (replaces ~40 us of scalar VALU). W streamed from L2 with
// rolling 3-slot register prefetch (wr[3][4] = 48 VGPR, distance 2).

template<int NSD, int KSTR>
static __device__ __forceinline__ void preload_w(bf16x8 (&wr)[3][4],
    const ushort_t* __restrict__ Wb, int slot, int ks, int wave, int lane){
  const int m = lane & 15, quad = lane >> 4;
  const int d0 = wave * (NSD*16);
  #pragma unroll
  for (int sd=0; sd<NSD; sd++)
    wr[slot][sd] = *(const bf16x8*)(Wb + (d0 + sd*16 + m)*KSTR + ks*32 + quad*8);
}

template<int NSD, int NKS>
static __device__ __forceinline__ void mfma_stream(bf16x8 (&wr)[3][4],
    const ushort_t* __restrict__ Wb, const ushort_t* __restrict__ src,
    f32x4 (&acc)[4][4], int wave, int lane){
  #pragma unroll
  for (int sn=0;sn<4;sn++)
    #pragma unroll
    for (int sd=0;sd<NSD;sd++)
      acc[sn][sd] = (f32x4){0.f,0.f,0.f,0.f};
  #pragma unroll
  for (int ks=0; ks<NKS; ks++){
    if (ks+2 < NKS) preload_w<NSD,256>(wr, Wb, (ks+2)%3, ks+2, wave, lane);
    bf16x8 a[4];
    #pragma unroll
    for (int sn=0;sn<4;sn++)
      a[sn] = *(const bf16x8*)(src + ((sn*512 + ks*64 + lane) << 3));
    #pragma unroll
    for (int sd=0;sd<NSD;sd++)
      #pragma unroll
      for (int sn=0;sn<4;sn++)
        acc[sn][sd] = __builtin_amdgcn_mfma_f32_16x16x32_bf16(a[sn], wr[ks%3][sd], acc[sn][sd], 0,0,0);
  }
}

// +bias, relu, write back into fragment-major layout (in-place), d64/wave
static __device__ __forceinline__ void epilogue_relu(const f32x4 (&acc)[4][4],
    const float* __restrict__ bias, ushort_t* __restrict__ dst, int wave, int lane){
  const int m = lane & 15, quad = lane >> 4;
  const int d0 = wave * 64;
  #pragma unroll
  for (int sd=0;sd<4;sd++){
    int d = d0 + sd*16 + m;
    float bv = bias[d];
    int colbase = (d>>5)*64 + ((d>>3)&3)*16;
    int j = d & 7;
    #pragma unroll
    for (int sn=0;sn<4;sn++){
      float v0 = fmaxf(acc[sn][sd][0] + bv, 0.f);
      float v1 = fmaxf(acc[sn][sd][1] + bv, 0.f);
      float v2 = fmaxf(acc[sn][sd][2] + bv, 0.f);
      float v3 = fmaxf(acc[sn][sd][3] + bv, 0.f);
      ushort2 p01 = cvtpk(v0, v1);
      ushort2 p23 = cvtpk(v2, v3);
      int base = (sn*512 + colbase + quad*4) << 3;
      dst[base +  0 + j] = p01.x;
      dst[base +  8 + j] = p01.y;
      dst[base + 16 + j] = p23.x;
      dst[base + 24 + j] = p23.y;
    }
  }
}

__global__ __launch_bounds__(256,3) void k_fused(
  const float* __restrict__ x, const float* __restrict__ mask,
  const ushort_t* __restrict__ w1b, const float* __restrict__ b1,
  const ushort_t* __restrict__ w2b, const float* __restrict__ b2,
  const ushort_t* __restrict__ w3b, const float* __restrict__ b3,
  const ushort_t* __restrict__ w4b, const float* __restrict__ b4,
  ushort_t* __restrict__ h4)
{
  __shared__ __align__(16) ushort_t Act[64*256];   // 32 KB, in-place across layers
  const int t    = threadIdx.x;
  const int bid  = blockIdx.x;
  const int b    = bid >> 3;
  const int n0   = (bid & 7) << 6;
  const int wave = t >> 6, lane = t & 63;

  bf16x8 wr[3][4];
  f32x4  acc[4][4];

  // Build layer-1 A-fragments (ks=0 chunks) straight from global x.
  // thread t: sn = t>>6, col = (t>>4)&3, n16 = t&15; chunk = sn*512 + col*16 + n16
  {
    const int sn = t >> 6, col = (t >> 4) & 3, n16 = t & 15;
    uint4 u4 = make_uint4(0u,0u,0u,0u);
    if (col == 0){
      const float* xp = x + (size_t)b*CIN*NPOS + n0 + sn*16 + n16;
      float x0 = xp[0], x1 = xp[NPOS], x2 = xp[2*NPOS], x3 = xp[3*NPOS], x4 = xp[4*NPOS];
      u4.x = cvtpk_u32(x0, x1);
      u4.y = cvtpk_u32(x2, x3);
      u4.z = cvtpk_u32(x4, 0.f);
    }
    *(uint4*)&Act[(sn*512 + col*16 + n16) << 3] = u4;
  }
  preload_w<4,32>(wr, w1b, 0, 0, wave, lane);   // W1 (K=32 padded) in flight
  __syncthreads();                              // (1) Act ks=0 = x-frags ready

  mfma_stream<4,1>(wr, w1b, Act, acc, wave, lane);   // layer 1
  preload_w<4,256>(wr, w2b, 0, 0, wave, lane);       // W2 head in flight
  preload_w<4,256>(wr, w2b, 1, 1, wave, lane);
  __syncthreads();                              // (2) x-frag reads done
  epilogue_relu(acc, b1, Act, wave, lane);
  __syncthreads();                              // (3) Act = h1

  mfma_stream<4,8>(wr, w2b, Act, acc, wave, lane);   // layer 2
  preload_w<4,256>(wr, w3b, 0, 0, wave, lane);
  preload_w<4,256>(wr, w3b, 1, 1, wave, lane);
  __syncthreads();                              // (4) h1 reads done
  epilogue_relu(acc, b2, Act, wave, lane);
  __syncthreads();                              // (5) Act = h2

  mfma_stream<4,8>(wr, w3b, Act, acc, wave, lane);   // layer 3
  preload_w<2,256>(wr, w4b, 0, 0, wave, lane);
  preload_w<2,256>(wr, w4b, 1, 1, wave, lane);
  __syncthreads();                              // (6) h2 reads done
  epilogue_relu(acc, b3, Act, wave, lane);
  __syncthreads();                              // (7) Act = h3

  mfma_stream<2,8>(wr, w4b, Act, acc, wave, lane);   // layer 4: wave owns 32 d
  {
    const int m = lane & 15, quad = lane >> 4;
    const float* maskrow = mask + (size_t)b*NPOS + n0;
    #pragma unroll
    for (int sd=0;sd<2;sd++){
      const int d = wave*32 + sd*16 + m;
      const float bv = b4[d];
      ushort_t* rowp = h4 + ((size_t)b*CO + d)*NPOS + n0;
      #pragma unroll
      for (int sn=0;sn<4;sn++){
        float4 mr = *(const float4*)(maskrow + sn*16 + quad*4);
        ushort2 p01 = cvtpk((acc[sn][sd][0] + bv) * (1.0f/512.0f) * mr.x,
                            (acc[sn][sd][1] + bv) * (1.0f/512.0f) * mr.y);
        ushort2 p23 = cvtpk((acc[sn][sd][2] + bv) * (1.0f/512.0f) * mr.z,
                            (acc[sn][sd][3] + bv) * (1.0f/512.0f) * mr.w);
        ushort4 p; p.x = p01.x; p.y = p01.y; p.z = p23.x; p.w = p23.y;
        *(ushort4*)(rowp + sn*16 + quad*4) = p;
      }
    }
  }
}

// ---------------- sort + pool ----------------
// Packed bitonic: TWO rows per wave, row0 in low u16 halves / row1 in high,
// 8 regs x (2x u16). Element index i = lane*8 + reg. Every shfl moves both
// rows; compares are v_pk_min/max_u16.
// bf16 -> order-preserving u16 key: key = u ^ (0x8000 | 0x7FFF*sign).
__global__ void k_pool(const ushort_t* __restrict__ h4, const float* __restrict__ pw,
                       float* __restrict__ out)
{
  const int lane = threadIdx.x & 63;
  const int wave = threadIdx.x >> 6;
  const size_t r0 = (size_t)blockIdx.x*8 + wave*2;   // rows r0, r0+1
  const int b0 = (int)(r0 >> 7), c0 = (int)(r0 & 127);
  const int b1_ = (int)((r0+1) >> 7), c1 = (int)((r0+1) & 127);

  uint4 ra = *(const uint4*)(h4 + r0*NPOS     + lane*8);
  uint4 rb = *(const uint4*)(h4 + (r0+1)*NPOS + lane*8);

  unsigned v[8];
  v[0] = (ra.x & 0xFFFFu) | (rb.x << 16);
  v[1] = (ra.x >> 16)     | (rb.x & 0xFFFF0000u);
  v[2] = (ra.y & 0xFFFFu) | (rb.y << 16);
  v[3] = (ra.y >> 16)     | (rb.y & 0xFFFF0000u);
  v[4] = (ra.z & 0xFFFFu) | (rb.z << 16);
  v[5] = (ra.z >> 16)     | (rb.z & 0xFFFF0000u);
  v[6] = (ra.w & 0xFFFFu) | (rb.w << 16);
  v[7] = (ra.w >> 16)     | (rb.w & 0xFFFF0000u);

  // bf16 -> sortable key (both halves at once)
  #pragma unroll
  for (int i=0;i<8;i++){
    unsigned sb = (v[i] >> 15) & 0x00010001u;
    v[i] = v[i] ^ 0x80008000u ^ (sb * 0x7FFFu);
  }

  #define CE_UP(a,b)   { unsigned mn=pk_min_u16(v[a],v[b]), mx=pk_max_u16(v[a],v[b]); v[a]=mn; v[b]=mx; }
  #define CE_DN(a,b)   { unsigned mn=pk_min_u16(v[a],v[b]), mx=pk_max_u16(v[a],v[b]); v[a]=mx; v[b]=mn; }
  #define CE_RT(a,b,up){ unsigned mn=pk_min_u16(v[a],v[b]), mx=pk_max_u16(v[a],v[b]); v[a]=(up)?mn:mx; v[b]=(up)?mx:mn; }

  // k=2 (j=1):
  CE_UP(0,1); CE_DN(2,3); CE_UP(4,5); CE_DN(6,7);
  // k=4:
  CE_UP(0,2); CE_UP(1,3); CE_DN(4,6); CE_DN(5,7);          // j=2
  CE_UP(0,1); CE_UP(2,3); CE_DN(4,5); CE_DN(6,7);          // j=1
  // k=8 (dir lane-dependent):
  {
    const bool up = (lane & 1) == 0;
    CE_RT(0,4,up); CE_RT(1,5,up); CE_RT(2,6,up); CE_RT(3,7,up);   // j=4
    CE_RT(0,2,up); CE_RT(1,3,up); CE_RT(4,6,up); CE_RT(5,7,up);   // j=2
    CE_RT(0,1,up); CE_RT(2,3,up); CE_RT(4,5,up); CE_RT(6,7,up);   // j=1
  }
  // k = 16 .. 512: cross-lane merges then in-lane cleanup
  #pragma unroll
  for (int k=16; k<=512; k<<=1){
    const bool up = (lane & (k>>3)) == 0;
    #pragma unroll
    for (int lm = (k>>4); lm >= 1; lm >>= 1){                      // j = lm*8
      const bool lower = (lane & lm) == 0;
      const bool keepmin = (up == lower);
      #pragma unroll
      for (int i=0;i<8;i++){
        unsigned o = __shfl_xor((int)v[i], lm);
        unsigned mn = pk_min_u16(v[i], (unsigned)o);
        unsigned mx = pk_max_u16(v[i], (unsigned)o);
        v[i] = keepmin ? mn : mx;
      }
    }
    CE_RT(0,4,up); CE_RT(1,5,up); CE_RT(2,6,up); CE_RT(3,7,up);   // j=4
    CE_RT(0,2,up); CE_RT(1,3,up); CE_RT(4,6,up); CE_RT(5,7,up);   // j=2
    CE_RT(0,1,up); CE_RT(2,3,up); CE_RT(4,5,up); CE_RT(6,7,up);   // j=1
  }
  #undef CE_UP
  #undef CE_DN
  #undef CE_RT

  // key -> bf16 bits (both halves)
  #pragma unroll
  for (int i=0;i<8;i++){
    unsigned sb = ((~v[i]) >> 15) & 0x00010001u;
    v[i] = v[i] ^ 0x80008000u ^ (sb * 0x7FFFu);
  }

  // ascending position i = lane*8 + reg -> descending rank r = 511 - i
  float s0 = 0.f, s1 = 0.f;
  #pragma unroll
  for (int i=0;i<8;i++){
    int rk = 511 - (lane*8 + i);
    float pos = (float)rk * (20.0f/511.0f);
    int idx = (int)pos; if (idx > 20) idx = 20;
    float frac = pos - (float)idx;
    int i2 = (idx+1 > 20) ? 20 : idx+1;
    float wl0 = pw[c0*21 + idx], wr0 = pw[c0*21 + i2];
    float wl1 = pw[c1*21 + idx], wr1 = pw[c1*21 + i2];
    union {unsigned u; float f;} lo, hi;
    lo.u = v[i] << 16;
    hi.u = v[i] & 0xFFFF0000u;
    s0 += lo.f * (wl0 + frac*(wr0-wl0));
    s1 += hi.f * (wl1 + frac*(wr1-wl1));
  }
  #pragma unroll
  for (int off=32; off>=1; off>>=1){
    s0 += __shfl_xor(s0, off);
    s1 += __shfl_xor(s1, off);
  }
  if (lane == 0){
    out[b0*129 + c0]  = s0;
    out[b1_*129 + c1] = s1;
  }
}

// ---------------- size feature ----------------
__global__ void k_size(const float* __restrict__ mask, float* __restrict__ out){
  const int b = blockIdx.x, lane = threadIdx.x;
  float s = 0.f;
  #pragma unroll
  for (int i=0;i<8;i++) s += mask[(size_t)b*NPOS + i*64 + lane];
  #pragma unroll
  for (int off=32; off>=1; off>>=1) s += __shfl_xor(s, off);
  if (lane == 0) out[b*129 + 128] = s * (1.0f/128.0f);  // mean*4 = sum/512*4
}

extern "C" void kernel_launch(void* const* d_in, const int* in_sizes, int n_in,
                              void* d_out, int out_size, void* d_ws, size_t ws_size,
                              hipStream_t stream){
  const float* x    = (const float*)d_in[0];
  const float* mask = (const float*)d_in[1];
  const float* w1   = (const float*)d_in[2];
  const float* b1   = (const float*)d_in[3];
  const float* w2   = (const float*)d_in[4];
  const float* b2   = (const float*)d_in[5];
  const float* w3   = (const float*)d_in[6];
  const float* b3   = (const float*)d_in[7];
  const float* w4   = (const float*)d_in[8];
  const float* b4   = (const float*)d_in[9];
  const float* pw   = (const float*)d_in[10];
  float* out = (float*)d_out;

  // ws: h4 bf16 (1024*128*512 = 128MB) | w2b | w3b | w4b | w1b
  ushort_t* h4  = (ushort_t*)d_ws;
  ushort_t* w2b = h4 + (size_t)1024*CO*NPOS;
  ushort_t* w3b = w2b + 65536;
  ushort_t* w4b = w3b + 65536;
  ushort_t* w1b = w4b + 32768;

  k_prep <<<672,   256, 0, stream>>>(w1, w2, w3, w4, w2b);
  k_fused<<<8192,  256, 0, stream>>>(x, mask, w1b, b1, w2b, b2, w3b, b3, w4b, b4, h4);
  k_pool <<<16384, 256, 0, stream>>>(h4, pw, out);
  k_size <<<1024,  64,  0, stream>>>(mask, out);
}

// Round 7
// 417.900 us; speedup vs baseline: 3.7175x; 1.2913x over previous
//
#include <hip/hip_runtime.h>
#include <hip/hip_bf16.h>

typedef __bf16 bf16x8 __attribute__((ext_vector_type(8)));
typedef float f32x4 __attribute__((ext_vector_type(4)));
typedef unsigned short ushort_t;

#define NPOS 512
#define CIN  5
#define CO   128

static __device__ __forceinline__ unsigned short f2bf(float f){
  union { __hip_bfloat16 h; unsigned short u; } cv;
  cv.h = __float2bfloat16(f);
  return cv.u;
}

// packed f32->bf16x2 (v_cvt_pk_bf16_f32 on gfx950) — RNE, 1 op per 2 values
static __device__ __forceinline__ unsigned cvtpk_u32(float a, float b){
  union { __hip_bfloat162 h2; unsigned u; } cv;
  cv.h2 = __float22bfloat162_rn(make_float2(a, b));
  return cv.u;
}

// packed u16 min/max (VOP3P) — one op handles two independent sort rows
static __device__ __forceinline__ unsigned pk_min_u16(unsigned a, unsigned b){
  unsigned d; asm("v_pk_min_u16 %0, %1, %2" : "=v"(d) : "v"(a), "v"(b)); return d;
}
static __device__ __forceinline__ unsigned pk_max_u16(unsigned a, unsigned b){
  unsigned d; asm("v_pk_max_u16 %0, %1, %2" : "=v"(d) : "v"(a), "v"(b)); return d;
}
// packed i16 max — relu on 2 packed bf16 (sign-correct; -0.0 -> +0.0)
static __device__ __forceinline__ unsigned pk_max_i16(unsigned a, unsigned b){
  unsigned d; asm("v_pk_max_i16 %0, %1, %2" : "=v"(d) : "v"(a), "v"(b)); return d;
}

// ---------------- weight fp32 -> bf16 prep ----------------
// o = [w2b 65536 | w3b 65536 | w4b 32768 | w1b 8192 (256 d x 32 k, k>=5 zero)]
__global__ void k_prep(const float* __restrict__ w1, const float* __restrict__ w2,
                       const float* __restrict__ w3, const float* __restrict__ w4,
                       ushort_t* __restrict__ o){
  int i = blockIdx.x*256 + threadIdx.x;   // grid covers 172032 exactly
  if (i < 65536)        o[i] = f2bf(w2[i]);
  else if (i < 131072)  o[i] = f2bf(w3[i-65536]);
  else if (i < 163840)  o[i] = f2bf(w4[i-131072]);
  else {
    int j = i - 163840;                   // 0..8191
    int d = j >> 5, k = j & 31;
    o[i] = (k < CIN) ? f2bf(w1[d*CIN + k]) : (ushort_t)0;
  }
}

// ---------------- fused conv1..conv4 (all-MFMA, 2-tile W reuse) ----------------
// Block owns (batch b, 128-n pair of tiles). Two in-place 32 KB Act buffers,
// fragment-major chunks: chunk(n,c) = (n>>4)*512 + (c>>5)*64 + ((c>>3)&3)*16 + (n&15),
// j-slot = c&7. A-read (sn,ks): chunk = sn*512 + ks*64 + lane (lane-seq b128).
// Inside each ks, one W fragment feeds MFMAs of BOTH tiles -> W L2 traffic
// halved vs R6 (was ~82 us/dispatch) and 32 MFMAs per prefetch window.
// Bias pre-loaded into acc (MFMA C-input); relu done packed post-cvt.

template<int NSD, int KSTR>
static __device__ __forceinline__ void preload_w(bf16x8 (&wr)[3][4],
    const ushort_t* __restrict__ Wb, int slot, int ks, int wave, int lane){
  const int m = lane & 15, quad = lane >> 4;
  const int d0 = wave * (NSD*16);
  #pragma unroll
  for (int sd=0; sd<NSD; sd++)
    wr[slot][sd] = *(const bf16x8*)(Wb + (d0 + sd*16 + m)*KSTR + ks*32 + quad*8);
}

template<int NSD, int NKS>
static __device__ __forceinline__ void mfma_layer2(bf16x8 (&wr)[3][4],
    const ushort_t* __restrict__ Wb,
    const ushort_t* __restrict__ A0, const ushort_t* __restrict__ A1,
    const float* __restrict__ bias,
    f32x4 (&c0)[4][4], f32x4 (&c1)[4][4], int wave, int lane){
  const int m = lane & 15;
  #pragma unroll
  for (int sd=0;sd<NSD;sd++){
    float bv = bias[wave*(NSD*16) + sd*16 + m];
    f32x4 bvv = (f32x4){bv,bv,bv,bv};
    #pragma unroll
    for (int sn=0;sn<4;sn++){ c0[sn][sd] = bvv; c1[sn][sd] = bvv; }
  }
  #pragma unroll
  for (int ks=0; ks<NKS; ks++){
    if (ks+2 < NKS) preload_w<NSD,256>(wr, Wb, (ks+2)%3, ks+2, wave, lane);
    bf16x8 a0[4], a1[4];
    #pragma unroll
    for (int sn=0;sn<4;sn++){
      a0[sn] = *(const bf16x8*)(A0 + ((sn*512 + ks*64 + lane) << 3));
      a1[sn] = *(const bf16x8*)(A1 + ((sn*512 + ks*64 + lane) << 3));
    }
    #pragma unroll
    for (int sd=0;sd<NSD;sd++){
      #pragma unroll
      for (int sn=0;sn<4;sn++){
        c0[sn][sd] = __builtin_amdgcn_mfma_f32_16x16x32_bf16(a0[sn], wr[ks%3][sd], c0[sn][sd], 0,0,0);
        c1[sn][sd] = __builtin_amdgcn_mfma_f32_16x16x32_bf16(a1[sn], wr[ks%3][sd], c1[sn][sd], 0,0,0);
      }
    }
  }
}

// +relu (packed, post-cvt), write back into fragment-major layout (in-place)
static __device__ __forceinline__ void epilogue_relu(const f32x4 (&c)[4][4],
    ushort_t* __restrict__ dst, int wave, int lane){
  const int m = lane & 15, quad = lane >> 4;
  const int d0 = wave * 64;
  #pragma unroll
  for (int sd=0;sd<4;sd++){
    int d = d0 + sd*16 + m;
    int colbase = (d>>5)*64 + ((d>>3)&3)*16;
    int j = d & 7;
    #pragma unroll
    for (int sn=0;sn<4;sn++){
      unsigned u01 = pk_max_i16(cvtpk_u32(c[sn][sd][0], c[sn][sd][1]), 0u);
      unsigned u23 = pk_max_i16(cvtpk_u32(c[sn][sd][2], c[sn][sd][3]), 0u);
      int base = (sn*512 + colbase + quad*4) << 3;
      dst[base +  0 + j] = (ushort_t)u01;
      dst[base +  8 + j] = (ushort_t)(u01 >> 16);
      dst[base + 16 + j] = (ushort_t)u23;
      dst[base + 24 + j] = (ushort_t)(u23 >> 16);
    }
  }
}

__global__ __launch_bounds__(256,2) void k_fused(
  const float* __restrict__ x, const float* __restrict__ mask,
  const ushort_t* __restrict__ w1b, const float* __restrict__ b1,
  const ushort_t* __restrict__ w2b, const float* __restrict__ b2,
  const ushort_t* __restrict__ w3b, const float* __restrict__ b3,
  const ushort_t* __restrict__ w4b, const float* __restrict__ b4,
  ushort_t* __restrict__ h4)
{
  __shared__ __align__(16) ushort_t Act0[64*256];   // 32 KB each, in-place
  __shared__ __align__(16) ushort_t Act1[64*256];
  const int t    = threadIdx.x;
  const int bid  = blockIdx.x;
  const int b    = bid >> 2;
  const int n0   = (bid & 3) << 7;       // tiles at n0 and n0+64
  const int wave = t >> 6, lane = t & 63;

  bf16x8 wr[3][4];
  f32x4  c0[4][4], c1[4][4];

  // Build layer-1 A-fragments (ks=0 chunks) straight from global x, both tiles.
  {
    const int sn = t >> 6, col = (t >> 4) & 3, n16 = t & 15;
    uint4 u0 = make_uint4(0u,0u,0u,0u), u1 = u0;
    if (col == 0){
      const float* xp = x + (size_t)b*CIN*NPOS + n0 + sn*16 + n16;
      u0.x = cvtpk_u32(xp[0],      xp[NPOS]);
      u0.y = cvtpk_u32(xp[2*NPOS], xp[3*NPOS]);
      u0.z = cvtpk_u32(xp[4*NPOS], 0.f);
      const float* xq = xp + 64;
      u1.x = cvtpk_u32(xq[0],      xq[NPOS]);
      u1.y = cvtpk_u32(xq[2*NPOS], xq[3*NPOS]);
      u1.z = cvtpk_u32(xq[4*NPOS], 0.f);
    }
    *(uint4*)&Act0[(sn*512 + col*16 + n16) << 3] = u0;
    *(uint4*)&Act1[(sn*512 + col*16 + n16) << 3] = u1;
  }
  preload_w<4,32>(wr, w1b, 0, 0, wave, lane);     // W1 (K=32 padded) in flight
  __syncthreads();                                // (1) x-frags ready

  mfma_layer2<4,1>(wr, w1b, Act0, Act1, b1, c0, c1, wave, lane);   // layer 1
  preload_w<4,256>(wr, w2b, 0, 0, wave, lane);    // W2 head in flight
  preload_w<4,256>(wr, w2b, 1, 1, wave, lane);
  __syncthreads();                                // (2) x-frag reads done
  epilogue_relu(c0, Act0, wave, lane);
  epilogue_relu(c1, Act1, wave, lane);
  __syncthreads();                                // (3) Act = h1

  mfma_layer2<4,8>(wr, w2b, Act0, Act1, b2, c0, c1, wave, lane);   // layer 2
  preload_w<4,256>(wr, w3b, 0, 0, wave, lane);
  preload_w<4,256>(wr, w3b, 1, 1, wave, lane);
  __syncthreads();                                // (4) h1 reads done
  epilogue_relu(c0, Act0, wave, lane);
  epilogue_relu(c1, Act1, wave, lane);
  __syncthreads();                                // (5) Act = h2

  mfma_layer2<4,8>(wr, w3b, Act0, Act1, b3, c0, c1, wave, lane);   // layer 3
  preload_w<2,256>(wr, w4b, 0, 0, wave, lane);
  preload_w<2,256>(wr, w4b, 1, 1, wave, lane);
  __syncthreads();                                // (6) h2 reads done
  epilogue_relu(c0, Act0, wave, lane);
  epilogue_relu(c1, Act1, wave, lane);
  __syncthreads();                                // (7) Act = h3

  mfma_layer2<2,8>(wr, w4b, Act0, Act1, b4, c0, c1, wave, lane);   // layer 4
  {
    const int m = lane & 15, quad = lane >> 4;
    const float* mk = mask + (size_t)b*NPOS + n0;
    #pragma unroll
    for (int sd=0;sd<2;sd++){
      const int d = wave*32 + sd*16 + m;
      ushort_t* rowp = h4 + ((size_t)b*CO + d)*NPOS + n0;
      #pragma unroll
      for (int sn=0;sn<4;sn++){
        float4 mr0 = *(const float4*)(mk + sn*16 + quad*4);
        float4 mr1 = *(const float4*)(mk + 64 + sn*16 + quad*4);
        unsigned q0 = cvtpk_u32(c0[sn][sd][0] * (1.0f/512.0f) * mr0.x,
                                c0[sn][sd][1] * (1.0f/512.0f) * mr0.y);
        unsigned q1 = cvtpk_u32(c0[sn][sd][2] * (1.0f/512.0f) * mr0.z,
                                c0[sn][sd][3] * (1.0f/512.0f) * mr0.w);
        *(uint2*)(rowp + sn*16 + quad*4) = make_uint2(q0, q1);
        unsigned p0 = cvtpk_u32(c1[sn][sd][0] * (1.0f/512.0f) * mr1.x,
                                c1[sn][sd][1] * (1.0f/512.0f) * mr1.y);
        unsigned p1 = cvtpk_u32(c1[sn][sd][2] * (1.0f/512.0f) * mr1.z,
                                c1[sn][sd][3] * (1.0f/512.0f) * mr1.w);
        *(uint2*)(rowp + 64 + sn*16 + quad*4) = make_uint2(p0, p1);
      }
    }
  }
}

// ---------------- sort + pool ----------------
// Packed bitonic: TWO rows per wave, row0 in low u16 halves / row1 in high,
// 8 regs x (2x u16). Element index i = lane*8 + reg. Every shfl moves both
// rows; compares are v_pk_min/max_u16.
// bf16 -> order-preserving u16 key: key = u ^ (0x8000 | 0x7FFF*sign).
__global__ void k_pool(const ushort_t* __restrict__ h4, const float* __restrict__ pw,
                       float* __restrict__ out)
{
  const int lane = threadIdx.x & 63;
  const int wave = threadIdx.x >> 6;
  const size_t r0 = (size_t)blockIdx.x*8 + wave*2;   // rows r0, r0+1
  const int b0 = (int)(r0 >> 7), c0 = (int)(r0 & 127);
  const int b1_ = (int)((r0+1) >> 7), c1 = (int)((r0+1) & 127);

  uint4 ra = *(const uint4*)(h4 + r0*NPOS     + lane*8);
  uint4 rb = *(const uint4*)(h4 + (r0+1)*NPOS + lane*8);

  unsigned v[8];
  v[0] = (ra.x & 0xFFFFu) | (rb.x << 16);
  v[1] = (ra.x >> 16)     | (rb.x & 0xFFFF0000u);
  v[2] = (ra.y & 0xFFFFu) | (rb.y << 16);
  v[3] = (ra.y >> 16)     | (rb.y & 0xFFFF0000u);
  v[4] = (ra.z & 0xFFFFu) | (rb.z << 16);
  v[5] = (ra.z >> 16)     | (rb.z & 0xFFFF0000u);
  v[6] = (ra.w & 0xFFFFu) | (rb.w << 16);
  v[7] = (ra.w >> 16)     | (rb.w & 0xFFFF0000u);

  // bf16 -> sortable key (both halves at once)
  #pragma unroll
  for (int i=0;i<8;i++){
    unsigned sb = (v[i] >> 15) & 0x00010001u;
    v[i] = v[i] ^ 0x80008000u ^ (sb * 0x7FFFu);
  }

  #define CE_UP(a,b)   { unsigned mn=pk_min_u16(v[a],v[b]), mx=pk_max_u16(v[a],v[b]); v[a]=mn; v[b]=mx; }
  #define CE_DN(a,b)   { unsigned mn=pk_min_u16(v[a],v[b]), mx=pk_max_u16(v[a],v[b]); v[a]=mx; v[b]=mn; }
  #define CE_RT(a,b,up){ unsigned mn=pk_min_u16(v[a],v[b]), mx=pk_max_u16(v[a],v[b]); v[a]=(up)?mn:mx; v[b]=(up)?mx:mn; }

  // k=2 (j=1):
  CE_UP(0,1); CE_DN(2,3); CE_UP(4,5); CE_DN(6,7);
  // k=4:
  CE_UP(0,2); CE_UP(1,3); CE_DN(4,6); CE_DN(5,7);          // j=2
  CE_UP(0,1); CE_UP(2,3); CE_DN(4,5); CE_DN(6,7);          // j=1
  // k=8 (dir lane-dependent):
  {
    const bool up = (lane & 1) == 0;
    CE_RT(0,4,up); CE_RT(1,5,up); CE_RT(2,6,up); CE_RT(3,7,up);   // j=4
    CE_RT(0,2,up); CE_RT(1,3,up); CE_RT(4,6,up); CE_RT(5,7,up);   // j=2
    CE_RT(0,1,up); CE_RT(2,3,up); CE_RT(4,5,up); CE_RT(6,7,up);   // j=1
  }
  // k = 16 .. 512: cross-lane merges then in-lane cleanup
  #pragma unroll
  for (int k=16; k<=512; k<<=1){
    const bool up = (lane & (k>>3)) == 0;
    #pragma unroll
    for (int lm = (k>>4); lm >= 1; lm >>= 1){                      // j = lm*8
      const bool lower = (lane & lm) == 0;
      const bool keepmin = (up == lower);
      #pragma unroll
      for (int i=0;i<8;i++){
        unsigned o = __shfl_xor((int)v[i], lm);
        unsigned mn = pk_min_u16(v[i], (unsigned)o);
        unsigned mx = pk_max_u16(v[i], (unsigned)o);
        v[i] = keepmin ? mn : mx;
      }
    }
    CE_RT(0,4,up); CE_RT(1,5,up); CE_RT(2,6,up); CE_RT(3,7,up);   // j=4
    CE_RT(0,2,up); CE_RT(1,3,up); CE_RT(4,6,up); CE_RT(5,7,up);   // j=2
    CE_RT(0,1,up); CE_RT(2,3,up); CE_RT(4,5,up); CE_RT(6,7,up);   // j=1
  }
  #undef CE_UP
  #undef CE_DN
  #undef CE_RT

  // key -> bf16 bits (both halves)
  #pragma unroll
  for (int i=0;i<8;i++){
    unsigned sb = ((~v[i]) >> 15) & 0x00010001u;
    v[i] = v[i] ^ 0x80008000u ^ (sb * 0x7FFFu);
  }

  // ascending position i = lane*8 + reg -> descending rank r = 511 - i
  float s0 = 0.f, s1 = 0.f;
  #pragma unroll
  for (int i=0;i<8;i++){
    int rk = 511 - (lane*8 + i);
    float pos = (float)rk * (20.0f/511.0f);
    int idx = (int)pos; if (idx > 20) idx = 20;
    float frac = pos - (float)idx;
    int i2 = (idx+1 > 20) ? 20 : idx+1;
    float wl0 = pw[c0*21 + idx], wr0 = pw[c0*21 + i2];
    float wl1 = pw[c1*21 + idx], wr1 = pw[c1*21 + i2];
    union {unsigned u; float f;} lo, hi;
    lo.u = v[i] << 16;
    hi.u = v[i] & 0xFFFF0000u;
    s0 += lo.f * (wl0 + frac*(wr0-wl0));
    s1 += hi.f * (wl1 + frac*(wr1-wl1));
  }
  #pragma unroll
  for (int off=32; off>=1; off>>=1){
    s0 += __shfl_xor(s0, off);
    s1 += __shfl_xor(s1, off);
  }
  if (lane == 0){
    out[b0*129 + c0]  = s0;
    out[b1_*129 + c1] = s1;
  }
}

// ---------------- size feature ----------------
__global__ void k_size(const float* __restrict__ mask, float* __restrict__ out){
  const int b = blockIdx.x, lane = threadIdx.x;
  float s = 0.f;
  #pragma unroll
  for (int i=0;i<8;i++) s += mask[(size_t)b*NPOS + i*64 + lane];
  #pragma unroll
  for (int off=32; off>=1; off>>=1) s += __shfl_xor(s, off);
  if (lane == 0) out[b*129 + 128] = s * (1.0f/128.0f);  // mean*4 = sum/512*4
}

extern "C" void kernel_launch(void* const* d_in, const int* in_sizes, int n_in,
                              void* d_out, int out_size, void* d_ws, size_t ws_size,
                              hipStream_t stream){
  const float* x    = (const float*)d_in[0];
  const float* mask = (const float*)d_in[1];
  const float* w1   = (const float*)d_in[2];
  const float* b1   = (const float*)d_in[3];
  const float* w2   = (const float*)d_in[4];
  const float* b2   = (const float*)d_in[5];
  const float* w3   = (const float*)d_in[6];
  const float* b3   = (const float*)d_in[7];
  const float* w4   = (const float*)d_in[8];
  const float* b4   = (const float*)d_in[9];
  const float* pw   = (const float*)d_in[10];
  float* out = (float*)d_out;

  // ws: h4 bf16 (1024*128*512 = 128MB) | w2b | w3b | w4b | w1b
  ushort_t* h4  = (ushort_t*)d_ws;
  ushort_t* w2b = h4 + (size_t)1024*CO*NPOS;
  ushort_t* w3b = w2b + 65536;
  ushort_t* w4b = w3b + 65536;
  ushort_t* w1b = w4b + 32768;

  k_prep <<<672,   256, 0, stream>>>(w1, w2, w3, w4, w2b);
  k_fused<<<4096,  256, 0, stream>>>(x, mask, w1b, b1, w2b, b2, w3b, b3, w4b, b4, h4);
  k_pool <<<16384, 256, 0, stream>>>(h4, pw, out);
  k_size <<<1024,  64,  0, stream>>>(mask, out);
}

// Round 8
// 393.935 us; speedup vs baseline: 3.9437x; 1.0608x over previous
//
#include <hip/hip_runtime.h>
#include <hip/hip_bf16.h>

typedef __bf16 bf16x8 __attribute__((ext_vector_type(8)));
typedef float f32x4 __attribute__((ext_vector_type(4)));
typedef unsigned short ushort_t;

#define NPOS 512
#define CIN  5
#define CO   128

static __device__ __forceinline__ unsigned short f2bf(float f){
  union { __hip_bfloat16 h; unsigned short u; } cv;
  cv.h = __float2bfloat16(f);
  return cv.u;
}

// packed f32->bf16x2 (v_cvt_pk_bf16_f32 on gfx950) — RNE, 1 op per 2 values
static __device__ __forceinline__ unsigned cvtpk_u32(float a, float b){
  union { __hip_bfloat162 h2; unsigned u; } cv;
  cv.h2 = __float22bfloat162_rn(make_float2(a, b));
  return cv.u;
}

// packed u16 min/max (VOP3P) — one op handles two independent sort rows
static __device__ __forceinline__ unsigned pk_min_u16(unsigned a, unsigned b){
  unsigned d; asm("v_pk_min_u16 %0, %1, %2" : "=v"(d) : "v"(a), "v"(b)); return d;
}
static __device__ __forceinline__ unsigned pk_max_u16(unsigned a, unsigned b){
  unsigned d; asm("v_pk_max_u16 %0, %1, %2" : "=v"(d) : "v"(a), "v"(b)); return d;
}
// packed i16 max — relu on 2 packed bf16 (sign-correct; -0.0 -> +0.0)
static __device__ __forceinline__ unsigned pk_max_i16(unsigned a, unsigned b){
  unsigned d; asm("v_pk_max_i16 %0, %1, %2" : "=v"(d) : "v"(a), "v"(b)); return d;
}

// DPP cross-lane fetch (VALU pipe, no DS): 0xB1=xor1, 0x4E=xor2, 0x128=xor8
template<int CTRL>
static __device__ __forceinline__ unsigned mov_dpp_u32(unsigned v){
  return (unsigned)__builtin_amdgcn_mov_dpp((int)v, CTRL, 0xf, 0xf, true);
}
template<int CTRL>
static __device__ __forceinline__ float fadd_dpp(float s){
  union {float f; int i;} u; u.f = s;
  union {int i; float f;} q; q.i = __builtin_amdgcn_mov_dpp(u.i, CTRL, 0xf, 0xf, true);
  return s + q.f;
}

// ---------------- weight fp32 -> bf16 prep (+ fspool weight table) ----------------
// o = [w2b 65536 | w3b 65536 | w4b 32768 | w1b 8192 (256 d x 32 k, k>=5 zero)]
// Wt[c][i] (f32, 128x512) = piecewise-linear pool weight at descending rank 511-i
__global__ void k_prep(const float* __restrict__ w1, const float* __restrict__ w2,
                       const float* __restrict__ w3, const float* __restrict__ w4,
                       const float* __restrict__ pw,
                       ushort_t* __restrict__ o, float* __restrict__ Wt){
  int i = blockIdx.x*256 + threadIdx.x;   // grid covers 237568 exactly
  if (i < 65536)        o[i] = f2bf(w2[i]);
  else if (i < 131072)  o[i] = f2bf(w3[i-65536]);
  else if (i < 163840)  o[i] = f2bf(w4[i-131072]);
  else if (i < 172032){
    int j = i - 163840;                   // 0..8191
    int d = j >> 5, k = j & 31;
    o[i] = (k < CIN) ? f2bf(w1[d*CIN + k]) : (ushort_t)0;
  } else {
    int j = i - 172032;                   // 0..65535
    int c = j >> 9, ii = j & 511;
    int rk = 511 - ii;
    float pos = (float)rk * (20.0f/511.0f);
    int idx = (int)pos; if (idx > 20) idx = 20;
    float frac = pos - (float)idx;
    int i2 = (idx+1 > 20) ? 20 : idx+1;
    float wl = pw[c*21 + idx], wr = pw[c*21 + i2];
    Wt[c*512 + ii] = wl + frac*(wr - wl);
  }
}

// ---------------- fused conv1..conv4 (all-MFMA, 2-tile W reuse) ----------------
// Block owns (batch b, 128-n pair of tiles). Two in-place 32 KB Act buffers,
// fragment-major chunks: chunk(n,c) = (n>>4)*512 + (c>>5)*64 + ((c>>3)&3)*16 + (n&15),
// j-slot = c&7. A-read (sn,ks): chunk = sn*512 + ks*64 + lane (lane-seq b128).
// Inside each ks, one W fragment feeds MFMAs of BOTH tiles -> W L2 traffic
// halved vs R6 and 32 MFMAs per prefetch window.
// Bias pre-loaded into acc (MFMA C-input); relu done packed post-cvt.

template<int NSD, int KSTR>
static __device__ __forceinline__ void preload_w(bf16x8 (&wr)[3][4],
    const ushort_t* __restrict__ Wb, int slot, int ks, int wave, int lane){
  const int m = lane & 15, quad = lane >> 4;
  const int d0 = wave * (NSD*16);
  #pragma unroll
  for (int sd=0; sd<NSD; sd++)
    wr[slot][sd] = *(const bf16x8*)(Wb + (d0 + sd*16 + m)*KSTR + ks*32 + quad*8);
}

template<int NSD, int NKS>
static __device__ __forceinline__ void mfma_layer2(bf16x8 (&wr)[3][4],
    const ushort_t* __restrict__ Wb,
    const ushort_t* __restrict__ A0, const ushort_t* __restrict__ A1,
    const float* __restrict__ bias,
    f32x4 (&c0)[4][4], f32x4 (&c1)[4][4], int wave, int lane){
  const int m = lane & 15;
  #pragma unroll
  for (int sd=0;sd<NSD;sd++){
    float bv = bias[wave*(NSD*16) + sd*16 + m];
    f32x4 bvv = (f32x4){bv,bv,bv,bv};
    #pragma unroll
    for (int sn=0;sn<4;sn++){ c0[sn][sd] = bvv; c1[sn][sd] = bvv; }
  }
  #pragma unroll
  for (int ks=0; ks<NKS; ks++){
    if (ks+2 < NKS) preload_w<NSD,256>(wr, Wb, (ks+2)%3, ks+2, wave, lane);
    bf16x8 a0[4], a1[4];
    #pragma unroll
    for (int sn=0;sn<4;sn++){
      a0[sn] = *(const bf16x8*)(A0 + ((sn*512 + ks*64 + lane) << 3));
      a1[sn] = *(const bf16x8*)(A1 + ((sn*512 + ks*64 + lane) << 3));
    }
    #pragma unroll
    for (int sd=0;sd<NSD;sd++){
      #pragma unroll
      for (int sn=0;sn<4;sn++){
        c0[sn][sd] = __builtin_amdgcn_mfma_f32_16x16x32_bf16(a0[sn], wr[ks%3][sd], c0[sn][sd], 0,0,0);
        c1[sn][sd] = __builtin_amdgcn_mfma_f32_16x16x32_bf16(a1[sn], wr[ks%3][sd], c1[sn][sd], 0,0,0);
      }
    }
  }
}

// +relu (packed, post-cvt), write back into fragment-major layout (in-place)
static __device__ __forceinline__ void epilogue_relu(const f32x4 (&c)[4][4],
    ushort_t* __restrict__ dst, int wave, int lane){
  const int m = lane & 15, quad = lane >> 4;
  const int d0 = wave * 64;
  #pragma unroll
  for (int sd=0;sd<4;sd++){
    int d = d0 + sd*16 + m;
    int colbase = (d>>5)*64 + ((d>>3)&3)*16;
    int j = d & 7;
    #pragma unroll
    for (int sn=0;sn<4;sn++){
      unsigned u01 = pk_max_i16(cvtpk_u32(c[sn][sd][0], c[sn][sd][1]), 0u);
      unsigned u23 = pk_max_i16(cvtpk_u32(c[sn][sd][2], c[sn][sd][3]), 0u);
      int base = (sn*512 + colbase + quad*4) << 3;
      dst[base +  0 + j] = (ushort_t)u01;
      dst[base +  8 + j] = (ushort_t)(u01 >> 16);
      dst[base + 16 + j] = (ushort_t)u23;
      dst[base + 24 + j] = (ushort_t)(u23 >> 16);
    }
  }
}

__global__ __launch_bounds__(256,2) void k_fused(
  const float* __restrict__ x, const float* __restrict__ mask,
  const ushort_t* __restrict__ w1b, const float* __restrict__ b1,
  const ushort_t* __restrict__ w2b, const float* __restrict__ b2,
  const ushort_t* __restrict__ w3b, const float* __restrict__ b3,
  const ushort_t* __restrict__ w4b, const float* __restrict__ b4,
  ushort_t* __restrict__ h4)
{
  __shared__ __align__(16) ushort_t Act0[64*256];   // 32 KB each, in-place
  __shared__ __align__(16) ushort_t Act1[64*256];
  const int t    = threadIdx.x;
  const int bid  = blockIdx.x;
  const int b    = bid >> 2;
  const int n0   = (bid & 3) << 7;       // tiles at n0 and n0+64
  const int wave = t >> 6, lane = t & 63;

  bf16x8 wr[3][4];
  f32x4  c0[4][4], c1[4][4];

  // Build layer-1 A-fragments (ks=0 chunks) straight from global x, both tiles.
  {
    const int sn = t >> 6, col = (t >> 4) & 3, n16 = t & 15;
    uint4 u0 = make_uint4(0u,0u,0u,0u), u1 = u0;
    if (col == 0){
      const float* xp = x + (size_t)b*CIN*NPOS + n0 + sn*16 + n16;
      u0.x = cvtpk_u32(xp[0],      xp[NPOS]);
      u0.y = cvtpk_u32(xp[2*NPOS], xp[3*NPOS]);
      u0.z = cvtpk_u32(xp[4*NPOS], 0.f);
      const float* xq = xp + 64;
      u1.x = cvtpk_u32(xq[0],      xq[NPOS]);
      u1.y = cvtpk_u32(xq[2*NPOS], xq[3*NPOS]);
      u1.z = cvtpk_u32(xq[4*NPOS], 0.f);
    }
    *(uint4*)&Act0[(sn*512 + col*16 + n16) << 3] = u0;
    *(uint4*)&Act1[(sn*512 + col*16 + n16) << 3] = u1;
  }
  preload_w<4,32>(wr, w1b, 0, 0, wave, lane);     // W1 (K=32 padded) in flight
  __syncthreads();                                // (1) x-frags ready

  mfma_layer2<4,1>(wr, w1b, Act0, Act1, b1, c0, c1, wave, lane);   // layer 1
  preload_w<4,256>(wr, w2b, 0, 0, wave, lane);    // W2 head in flight
  preload_w<4,256>(wr, w2b, 1, 1, wave, lane);
  __syncthreads();                                // (2) x-frag reads done
  epilogue_relu(c0, Act0, wave, lane);
  epilogue_relu(c1, Act1, wave, lane);
  __syncthreads();                                // (3) Act = h1

  mfma_layer2<4,8>(wr, w2b, Act0, Act1, b2, c0, c1, wave, lane);   // layer 2
  preload_w<4,256>(wr, w3b, 0, 0, wave, lane);
  preload_w<4,256>(wr, w3b, 1, 1, wave, lane);
  __syncthreads();                                // (4) h1 reads done
  epilogue_relu(c0, Act0, wave, lane);
  epilogue_relu(c1, Act1, wave, lane);
  __syncthreads();                                // (5) Act = h2

  mfma_layer2<4,8>(wr, w3b, Act0, Act1, b3, c0, c1, wave, lane);   // layer 3
  preload_w<2,256>(wr, w4b, 0, 0, wave, lane);
  preload_w<2,256>(wr, w4b, 1, 1, wave, lane);
  __syncthreads();                                // (6) h2 reads done
  epilogue_relu(c0, Act0, wave, lane);
  epilogue_relu(c1, Act1, wave, lane);
  __syncthreads();                                // (7) Act = h3

  mfma_layer2<2,8>(wr, w4b, Act0, Act1, b4, c0, c1, wave, lane);   // layer 4
  {
    const int m = lane & 15, quad = lane >> 4;
    const float* mk = mask + (size_t)b*NPOS + n0;
    #pragma unroll
    for (int sd=0;sd<2;sd++){
      const int d = wave*32 + sd*16 + m;
      ushort_t* rowp = h4 + ((size_t)b*CO + d)*NPOS + n0;
      #pragma unroll
      for (int sn=0;sn<4;sn++){
        float4 mr0 = *(const float4*)(mk + sn*16 + quad*4);
        float4 mr1 = *(const float4*)(mk + 64 + sn*16 + quad*4);
        unsigned q0 = cvtpk_u32(c0[sn][sd][0] * (1.0f/512.0f) * mr0.x,
                                c0[sn][sd][1] * (1.0f/512.0f) * mr0.y);
        unsigned q1 = cvtpk_u32(c0[sn][sd][2] * (1.0f/512.0f) * mr0.z,
                                c0[sn][sd][3] * (1.0f/512.0f) * mr0.w);
        *(uint2*)(rowp + sn*16 + quad*4) = make_uint2(q0, q1);
        unsigned p0 = cvtpk_u32(c1[sn][sd][0] * (1.0f/512.0f) * mr1.x,
                                c1[sn][sd][1] * (1.0f/512.0f) * mr1.y);
        unsigned p1 = cvtpk_u32(c1[sn][sd][2] * (1.0f/512.0f) * mr1.z,
                                c1[sn][sd][3] * (1.0f/512.0f) * mr1.w);
        *(uint2*)(rowp + 64 + sn*16 + quad*4) = make_uint2(p0, p1);
      }
    }
  }
}

// ---------------- sort + pool ----------------
// Packed bitonic, TWO rows per wave (row0 low u16 / row1 high u16 of 8 regs).
// DS-pipe relief: xor-distances 1,2,8 go through DPP (VALU pipe, quad_perm
// 0xB1/0x4E + row_ror:8 0x128); only 4,16,32 use __shfl_xor. Direction-flip:
// values on "descending" lanes are bit-NOTted per phase so every CE is fixed
// ascending (min(~a,~b) = ~max(a,b)). Weight lookup from precomputed Wt.

static __device__ __forceinline__ void ce_up(unsigned &a, unsigned &b){
  unsigned mn = pk_min_u16(a,b), mx = pk_max_u16(a,b); a = mn; b = mx;
}
static __device__ __forceinline__ void ce_dn(unsigned &a, unsigned &b){
  unsigned mn = pk_min_u16(a,b), mx = pk_max_u16(a,b); a = mx; b = mn;
}
static __device__ __forceinline__ void clean8(unsigned (&v)[8]){   // j=4,2,1 ascending
  ce_up(v[0],v[4]); ce_up(v[1],v[5]); ce_up(v[2],v[6]); ce_up(v[3],v[7]);
  ce_up(v[0],v[2]); ce_up(v[1],v[3]); ce_up(v[4],v[6]); ce_up(v[5],v[7]);
  ce_up(v[0],v[1]); ce_up(v[2],v[3]); ce_up(v[4],v[5]); ce_up(v[6],v[7]);
}
static __device__ __forceinline__ void flip8(unsigned (&v)[8], unsigned f){
  #pragma unroll
  for (int i=0;i<8;i++) v[i] ^= f;
}
template<int CTRL>
static __device__ __forceinline__ void xr_dpp(unsigned (&v)[8], bool low){
  #pragma unroll
  for (int i=0;i<8;i++){
    unsigned p = mov_dpp_u32<CTRL>(v[i]);
    unsigned mn = pk_min_u16(v[i], p), mx = pk_max_u16(v[i], p);
    v[i] = low ? mn : mx;
  }
}
static __device__ __forceinline__ void xr_shfl(unsigned (&v)[8], int lm, bool low){
  #pragma unroll
  for (int i=0;i<8;i++){
    unsigned p = (unsigned)__shfl_xor((int)v[i], lm);
    unsigned mn = pk_min_u16(v[i], p), mx = pk_max_u16(v[i], p);
    v[i] = low ? mn : mx;
  }
}

__global__ void k_pool(const ushort_t* __restrict__ h4, const float* __restrict__ Wt,
                       float* __restrict__ out)
{
  const int lane = threadIdx.x & 63;
  const int wave = threadIdx.x >> 6;
  const size_t r0 = (size_t)blockIdx.x*8 + wave*2;   // rows r0, r0+1
  const int b0 = (int)(r0 >> 7), c0 = (int)(r0 & 127);
  const int b1_ = (int)((r0+1) >> 7), c1 = (int)((r0+1) & 127);

  uint4 ra = *(const uint4*)(h4 + r0*NPOS     + lane*8);
  uint4 rb = *(const uint4*)(h4 + (r0+1)*NPOS + lane*8);

  unsigned v[8];
  v[0] = (ra.x & 0xFFFFu) | (rb.x << 16);
  v[1] = (ra.x >> 16)     | (rb.x & 0xFFFF0000u);
  v[2] = (ra.y & 0xFFFFu) | (rb.y << 16);
  v[3] = (ra.y >> 16)     | (rb.y & 0xFFFF0000u);
  v[4] = (ra.z & 0xFFFFu) | (rb.z << 16);
  v[5] = (ra.z >> 16)     | (rb.z & 0xFFFF0000u);
  v[6] = (ra.w & 0xFFFFu) | (rb.w << 16);
  v[7] = (ra.w >> 16)     | (rb.w & 0xFFFF0000u);

  // bf16 -> sortable u16 key (both halves at once)
  #pragma unroll
  for (int i=0;i<8;i++){
    unsigned sb = (v[i] >> 15) & 0x00010001u;
    v[i] = v[i] ^ 0x80008000u ^ (sb * 0x7FFFu);
  }

  const bool lo1  = (lane & 1)  == 0;
  const bool lo2  = (lane & 2)  == 0;
  const bool lo4  = (lane & 4)  == 0;
  const bool lo8  = (lane & 8)  == 0;
  const bool lo16 = (lane & 16) == 0;
  const bool lo32 = (lane & 32) == 0;

  // phase-direction flip masks (up_k false -> NOT the values)
  const unsigned F8   = (lane & 1)  ? 0xFFFFFFFFu : 0u;
  const unsigned F16  = (lane & 2)  ? 0xFFFFFFFFu : 0u;
  const unsigned F32  = (lane & 4)  ? 0xFFFFFFFFu : 0u;
  const unsigned F64  = (lane & 8)  ? 0xFFFFFFFFu : 0u;
  const unsigned F128 = (lane & 16) ? 0xFFFFFFFFu : 0u;
  const unsigned F256 = (lane & 32) ? 0xFFFFFFFFu : 0u;

  // k=2, k=4 presort (fixed directions)
  ce_up(v[0],v[1]); ce_dn(v[2],v[3]); ce_up(v[4],v[5]); ce_dn(v[6],v[7]);
  ce_up(v[0],v[2]); ce_up(v[1],v[3]); ce_dn(v[4],v[6]); ce_dn(v[5],v[7]);
  ce_up(v[0],v[1]); ce_up(v[2],v[3]); ce_dn(v[4],v[5]); ce_dn(v[6],v[7]);

  flip8(v, F8);                                   // k=8 (in-lane only)
  clean8(v);
  flip8(v, F8 ^ F16);                             // k=16
  xr_dpp<0xB1>(v, lo1);
  clean8(v);
  flip8(v, F16 ^ F32);                            // k=32
  xr_dpp<0x4E>(v, lo2); xr_dpp<0xB1>(v, lo1);
  clean8(v);
  flip8(v, F32 ^ F64);                            // k=64
  xr_shfl(v, 4, lo4); xr_dpp<0x4E>(v, lo2); xr_dpp<0xB1>(v, lo1);
  clean8(v);
  flip8(v, F64 ^ F128);                           // k=128
  xr_dpp<0x128>(v, lo8); xr_shfl(v, 4, lo4); xr_dpp<0x4E>(v, lo2); xr_dpp<0xB1>(v, lo1);
  clean8(v);
  flip8(v, F128 ^ F256);                          // k=256
  xr_shfl(v, 16, lo16); xr_dpp<0x128>(v, lo8); xr_shfl(v, 4, lo4);
  xr_dpp<0x4E>(v, lo2); xr_dpp<0xB1>(v, lo1);
  clean8(v);
  flip8(v, F256);                                 // k=512 runs unflipped
  xr_shfl(v, 32, lo32); xr_shfl(v, 16, lo16); xr_dpp<0x128>(v, lo8);
  xr_shfl(v, 4, lo4); xr_dpp<0x4E>(v, lo2); xr_dpp<0xB1>(v, lo1);
  clean8(v);

  // key -> bf16 bits (both halves)
  #pragma unroll
  for (int i=0;i<8;i++){
    unsigned sb = ((~v[i]) >> 15) & 0x00010001u;
    v[i] = v[i] ^ 0x80008000u ^ (sb * 0x7FFFu);
  }

  // dot with precomputed weights (ascending position i = lane*8 + reg)
  float w0[8], w1a[8];
  *(float4*)&w0[0]  = *(const float4*)(Wt + c0*512 + lane*8);
  *(float4*)&w0[4]  = *(const float4*)(Wt + c0*512 + lane*8 + 4);
  *(float4*)&w1a[0] = *(const float4*)(Wt + c1*512 + lane*8);
  *(float4*)&w1a[4] = *(const float4*)(Wt + c1*512 + lane*8 + 4);

  float s0 = 0.f, s1 = 0.f;
  #pragma unroll
  for (int i=0;i<8;i++){
    union {unsigned u; float f;} lo, hi;
    lo.u = v[i] << 16;
    hi.u = v[i] & 0xFFFF0000u;
    s0 = fmaf(lo.f, w0[i],  s0);
    s1 = fmaf(hi.f, w1a[i], s1);
  }
  s0 = fadd_dpp<0xB1>(s0);  s1 = fadd_dpp<0xB1>(s1);
  s0 = fadd_dpp<0x4E>(s0);  s1 = fadd_dpp<0x4E>(s1);
  s0 = fadd_dpp<0x128>(s0); s1 = fadd_dpp<0x128>(s1);
  s0 += __shfl_xor(s0, 4);  s1 += __shfl_xor(s1, 4);
  s0 += __shfl_xor(s0, 16); s1 += __shfl_xor(s1, 16);
  s0 += __shfl_xor(s0, 32); s1 += __shfl_xor(s1, 32);

  if (lane == 0){
    out[b0*129 + c0]  = s0;
    out[b1_*129 + c1] = s1;
  }
}

// ---------------- size feature ----------------
__global__ void k_size(const float* __restrict__ mask, float* __restrict__ out){
  const int b = blockIdx.x, lane = threadIdx.x;
  float s = 0.f;
  #pragma unroll
  for (int i=0;i<8;i++) s += mask[(size_t)b*NPOS + i*64 + lane];
  #pragma unroll
  for (int off=32; off>=1; off>>=1) s += __shfl_xor(s, off);
  if (lane == 0) out[b*129 + 128] = s * (1.0f/128.0f);  // mean*4 = sum/512*4
}

extern "C" void kernel_launch(void* const* d_in, const int* in_sizes, int n_in,
                              void* d_out, int out_size, void* d_ws, size_t ws_size,
                              hipStream_t stream){
  const float* x    = (const float*)d_in[0];
  const float* mask = (const float*)d_in[1];
  const float* w1   = (const float*)d_in[2];
  const float* b1   = (const float*)d_in[3];
  const float* w2   = (const float*)d_in[4];
  const float* b2   = (const float*)d_in[5];
  const float* w3   = (const float*)d_in[6];
  const float* b3   = (const float*)d_in[7];
  const float* w4   = (const float*)d_in[8];
  const float* b4   = (const float*)d_in[9];
  const float* pw   = (const float*)d_in[10];
  float* out = (float*)d_out;

  // ws: h4 bf16 (1024*128*512 = 128MB) | w2b | w3b | w4b | w1b | Wt (f32 128x512)
  ushort_t* h4  = (ushort_t*)d_ws;
  ushort_t* w2b = h4 + (size_t)1024*CO*NPOS;
  ushort_t* w3b = w2b + 65536;
  ushort_t* w4b = w3b + 65536;
  ushort_t* w1b = w4b + 32768;
  float*    Wt  = (float*)(w1b + 8192);

  k_prep <<<928,   256, 0, stream>>>(w1, w2, w3, w4, pw, w2b, Wt);
  k_fused<<<4096,  256, 0, stream>>>(x, mask, w1b, b1, w2b, b2, w3b, b3, w4b, b4, h4);
  k_pool <<<16384, 256, 0, stream>>>(h4, Wt, out);
  k_size <<<1024,  64,  0, stream>>>(mask, out);
}

// Round 9
// 374.551 us; speedup vs baseline: 4.1478x; 1.0518x over previous
//
#include <hip/hip_runtime.h>
#include <hip/hip_bf16.h>

typedef __bf16 bf16x8 __attribute__((ext_vector_type(8)));
typedef float f32x4 __attribute__((ext_vector_type(4)));
typedef unsigned short ushort_t;

#define NPOS 512
#define CIN  5
#define CO   128

static __device__ __forceinline__ unsigned short f2bf(float f){
  union { __hip_bfloat16 h; unsigned short u; } cv;
  cv.h = __float2bfloat16(f);
  return cv.u;
}

// packed f32->bf16x2 (v_cvt_pk_bf16_f32 on gfx950) — RNE, 1 op per 2 values
static __device__ __forceinline__ unsigned cvtpk_u32(float a, float b){
  union { __hip_bfloat162 h2; unsigned u; } cv;
  cv.h2 = __float22bfloat162_rn(make_float2(a, b));
  return cv.u;
}

// packed u16 min/max (VOP3P) — one op handles two independent sort rows
static __device__ __forceinline__ unsigned pk_min_u16(unsigned a, unsigned b){
  unsigned d; asm("v_pk_min_u16 %0, %1, %2" : "=v"(d) : "v"(a), "v"(b)); return d;
}
static __device__ __forceinline__ unsigned pk_max_u16(unsigned a, unsigned b){
  unsigned d; asm("v_pk_max_u16 %0, %1, %2" : "=v"(d) : "v"(a), "v"(b)); return d;
}
// packed i16 max — relu on 2 packed bf16 (sign-correct; -0.0 -> +0.0)
static __device__ __forceinline__ unsigned pk_max_i16(unsigned a, unsigned b){
  unsigned d; asm("v_pk_max_i16 %0, %1, %2" : "=v"(d) : "v"(a), "v"(b)); return d;
}

// DPP cross-lane fetch (VALU pipe, no DS): 0xB1=xor1, 0x4E=xor2, 0x128=xor8
template<int CTRL>
static __device__ __forceinline__ unsigned mov_dpp_u32(unsigned v){
  return (unsigned)__builtin_amdgcn_mov_dpp((int)v, CTRL, 0xf, 0xf, true);
}
template<int CTRL>
static __device__ __forceinline__ float fadd_dpp(float s){
  union {float f; int i;} u; u.f = s;
  union {int i; float f;} q; q.i = __builtin_amdgcn_mov_dpp(u.i, CTRL, 0xf, 0xf, true);
  return s + q.f;
}

// ---------------- weight fp32 -> bf16 prep (+ fspool weight table) ----------------
// o = [w2b 65536 | w3b 65536 | w4b 32768 | w1b 8192 (256 d x 32 k, k>=5 zero)]
// Wt[c][i] (f32, 128x512) = piecewise-linear pool weight at descending rank 511-i
__global__ void k_prep(const float* __restrict__ w1, const float* __restrict__ w2,
                       const float* __restrict__ w3, const float* __restrict__ w4,
                       const float* __restrict__ pw,
                       ushort_t* __restrict__ o, float* __restrict__ Wt){
  int i = blockIdx.x*256 + threadIdx.x;   // grid covers 237568 exactly
  if (i < 65536)        o[i] = f2bf(w2[i]);
  else if (i < 131072)  o[i] = f2bf(w3[i-65536]);
  else if (i < 163840)  o[i] = f2bf(w4[i-131072]);
  else if (i < 172032){
    int j = i - 163840;                   // 0..8191
    int d = j >> 5, k = j & 31;
    o[i] = (k < CIN) ? f2bf(w1[d*CIN + k]) : (ushort_t)0;
  } else {
    int j = i - 172032;                   // 0..65535
    int c = j >> 9, ii = j & 511;
    int rk = 511 - ii;
    float pos = (float)rk * (20.0f/511.0f);
    int idx = (int)pos; if (idx > 20) idx = 20;
    float frac = pos - (float)idx;
    int i2 = (idx+1 > 20) ? 20 : idx+1;
    float wl = pw[c*21 + idx], wr = pw[c*21 + i2];
    Wt[c*512 + ii] = wl + frac*(wr - wl);
  }
}

// ---------------- fused conv1..conv4 (all-MFMA, 2-tile W reuse) ----------------
// Block owns (batch b, 128-n pair of tiles). Two in-place 32 KB Act buffers,
// fragment-major chunks: chunk(n,c) = (n>>4)*512 + (c>>5)*64 + ((c>>3)&3)*16 + (n&15),
// j-slot = c&7. Act-read (nb,ks): chunk = nb*512 + ks*64 + lane (lane-seq b128).
//
// R9: layers 1-3 pass W as the MFMA *A*-operand and Act as *B* (per-lane frag
// data identical under the role swap), flipping C/D to lane=n, quad*4+reg =
// 4 consecutive d. Epilogue packs those into ONE ds_write_b64 per acc tile
// (was 4x ds_write_b16 scatter -> ~2200 DS cyc/wave + 1.26e7 conflict cyc).
// Layer 4 keeps Act-as-A so the global h4 store stays n-consecutive.

template<int NSD, int KSTR>
static __device__ __forceinline__ void preload_w(bf16x8 (&wr)[3][4],
    const ushort_t* __restrict__ Wb, int slot, int ks, int wave, int lane){
  const int m = lane & 15, quad = lane >> 4;
  const int d0 = wave * (NSD*16);
  #pragma unroll
  for (int sd=0; sd<NSD; sd++)
    wr[slot][sd] = *(const bf16x8*)(Wb + (d0 + sd*16 + m)*KSTR + ks*32 + quad*8);
}

// layers 1-3: W as A-operand, Act as B-operand. acc[nb][db]:
//   n = nb*16 + (lane&15), d = wave*64 + db*16 + quad*4 + rg
template<int NKS>
static __device__ __forceinline__ void mfma_WA(bf16x8 (&wr)[3][4],
    const ushort_t* __restrict__ Wb,
    const ushort_t* __restrict__ A0, const ushort_t* __restrict__ A1,
    const float* __restrict__ bias,
    f32x4 (&c0)[4][4], f32x4 (&c1)[4][4], int wave, int lane){
  const int quad = lane >> 4;
  #pragma unroll
  for (int db=0; db<4; db++){
    float4 b4v = *(const float4*)(bias + wave*64 + db*16 + quad*4);
    f32x4 bvv = (f32x4){b4v.x, b4v.y, b4v.z, b4v.w};
    #pragma unroll
    for (int nb=0; nb<4; nb++){ c0[nb][db] = bvv; c1[nb][db] = bvv; }
  }
  #pragma unroll
  for (int ks=0; ks<NKS; ks++){
    if (ks+2 < NKS) preload_w<4,256>(wr, Wb, (ks+2)%3, ks+2, wave, lane);
    bf16x8 a0[4], a1[4];
    #pragma unroll
    for (int nb=0; nb<4; nb++){
      a0[nb] = *(const bf16x8*)(A0 + ((nb*512 + ks*64 + lane) << 3));
      a1[nb] = *(const bf16x8*)(A1 + ((nb*512 + ks*64 + lane) << 3));
    }
    #pragma unroll
    for (int db=0; db<4; db++){
      #pragma unroll
      for (int nb=0; nb<4; nb++){
        c0[nb][db] = __builtin_amdgcn_mfma_f32_16x16x32_bf16(wr[ks%3][db], a0[nb], c0[nb][db], 0,0,0);
        c1[nb][db] = __builtin_amdgcn_mfma_f32_16x16x32_bf16(wr[ks%3][db], a1[nb], c1[nb][db], 0,0,0);
      }
    }
  }
}

// layer 4: Act as A-operand (old orientation). acc[sn][sd]:
//   n = sn*16 + quad*4 + rg, d = wave*32 + sd*16 + (lane&15)
static __device__ __forceinline__ void mfma_L4(bf16x8 (&wr)[3][4],
    const ushort_t* __restrict__ Wb,
    const ushort_t* __restrict__ A0, const ushort_t* __restrict__ A1,
    const float* __restrict__ bias,
    f32x4 (&c0)[4][4], f32x4 (&c1)[4][4], int wave, int lane){
  const int m = lane & 15;
  #pragma unroll
  for (int sd=0; sd<2; sd++){
    float bv = bias[wave*32 + sd*16 + m];
    f32x4 bvv = (f32x4){bv,bv,bv,bv};
    #pragma unroll
    for (int sn=0; sn<4; sn++){ c0[sn][sd] = bvv; c1[sn][sd] = bvv; }
  }
  #pragma unroll
  for (int ks=0; ks<8; ks++){
    if (ks+2 < 8) preload_w<2,256>(wr, Wb, (ks+2)%3, ks+2, wave, lane);
    bf16x8 a0[4], a1[4];
    #pragma unroll
    for (int sn=0; sn<4; sn++){
      a0[sn] = *(const bf16x8*)(A0 + ((sn*512 + ks*64 + lane) << 3));
      a1[sn] = *(const bf16x8*)(A1 + ((sn*512 + ks*64 + lane) << 3));
    }
    #pragma unroll
    for (int sd=0; sd<2; sd++){
      #pragma unroll
      for (int sn=0; sn<4; sn++){
        c0[sn][sd] = __builtin_amdgcn_mfma_f32_16x16x32_bf16(a0[sn], wr[ks%3][sd], c0[sn][sd], 0,0,0);
        c1[sn][sd] = __builtin_amdgcn_mfma_f32_16x16x32_bf16(a1[sn], wr[ks%3][sd], c1[sn][sd], 0,0,0);
      }
    }
  }
}

// layers 1-3 epilogue: +relu, ONE b64 write per acc tile (4 consecutive c)
static __device__ __forceinline__ void epilogue_relu(const f32x4 (&c)[4][4],
    ushort_t* __restrict__ dst, int wave, int lane){
  const int m = lane & 15, quad = lane >> 4;
  #pragma unroll
  for (int db=0; db<4; db++){
    // c-base for this lane: wave*64 + db*16 + quad*4
    int cb    = wave*64 + db*16 + quad*4;
    int colpt = (cb>>5)*64 + ((cb>>3)&3)*16;     // chunk col part
    int half  = (quad & 1) ? 4 : 0;              // 8B half within 16B chunk
    #pragma unroll
    for (int nb=0; nb<4; nb++){
      unsigned u01 = pk_max_i16(cvtpk_u32(c[nb][db][0], c[nb][db][1]), 0u);
      unsigned u23 = pk_max_i16(cvtpk_u32(c[nb][db][2], c[nb][db][3]), 0u);
      int chunk = nb*512 + colpt + m;
      *(uint2*)&dst[(chunk << 3) + half] = make_uint2(u01, u23);
    }
  }
}

__global__ __launch_bounds__(256,2) void k_fused(
  const float* __restrict__ x, const float* __restrict__ mask,
  const ushort_t* __restrict__ w1b, const float* __restrict__ b1,
  const ushort_t* __restrict__ w2b, const float* __restrict__ b2,
  const ushort_t* __restrict__ w3b, const float* __restrict__ b3,
  const ushort_t* __restrict__ w4b, const float* __restrict__ b4,
  ushort_t* __restrict__ h4)
{
  __shared__ __align__(16) ushort_t Act0[64*256];   // 32 KB each, in-place
  __shared__ __align__(16) ushort_t Act1[64*256];
  const int t    = threadIdx.x;
  const int bid  = blockIdx.x;
  const int b    = bid >> 2;
  const int n0   = (bid & 3) << 7;       // tiles at n0 and n0+64
  const int wave = t >> 6, lane = t & 63;

  bf16x8 wr[3][4];
  f32x4  c0[4][4], c1[4][4];

  // Build layer-1 fragments (ks=0 chunks) straight from global x, both tiles.
  {
    const int sn = t >> 6, col = (t >> 4) & 3, n16 = t & 15;
    uint4 u0 = make_uint4(0u,0u,0u,0u), u1 = u0;
    if (col == 0){
      const float* xp = x + (size_t)b*CIN*NPOS + n0 + sn*16 + n16;
      u0.x = cvtpk_u32(xp[0],      xp[NPOS]);
      u0.y = cvtpk_u32(xp[2*NPOS], xp[3*NPOS]);
      u0.z = cvtpk_u32(xp[4*NPOS], 0.f);
      const float* xq = xp + 64;
      u1.x = cvtpk_u32(xq[0],      xq[NPOS]);
      u1.y = cvtpk_u32(xq[2*NPOS], xq[3*NPOS]);
      u1.z = cvtpk_u32(xq[4*NPOS], 0.f);
    }
    *(uint4*)&Act0[(sn*512 + col*16 + n16) << 3] = u0;
    *(uint4*)&Act1[(sn*512 + col*16 + n16) << 3] = u1;
  }
  preload_w<4,32>(wr, w1b, 0, 0, wave, lane);     // W1 (K=32 padded) in flight
  __syncthreads();                                // (1) x-frags ready

  mfma_WA<1>(wr, w1b, Act0, Act1, b1, c0, c1, wave, lane);   // layer 1
  preload_w<4,256>(wr, w2b, 0, 0, wave, lane);    // W2 head in flight
  preload_w<4,256>(wr, w2b, 1, 1, wave, lane);
  __syncthreads();                                // (2) x-frag reads done
  epilogue_relu(c0, Act0, wave, lane);
  epilogue_relu(c1, Act1, wave, lane);
  __syncthreads();                                // (3) Act = h1

  mfma_WA<8>(wr, w2b, Act0, Act1, b2, c0, c1, wave, lane);   // layer 2
  preload_w<4,256>(wr, w3b, 0, 0, wave, lane);
  preload_w<4,256>(wr, w3b, 1, 1, wave, lane);
  __syncthreads();                                // (4) h1 reads done
  epilogue_relu(c0, Act0, wave, lane);
  epilogue_relu(c1, Act1, wave, lane);
  __syncthreads();                                // (5) Act = h2

  mfma_WA<8>(wr, w3b, Act0, Act1, b3, c0, c1, wave, lane);   // layer 3
  preload_w<2,256>(wr, w4b, 0, 0, wave, lane);
  preload_w<2,256>(wr, w4b, 1, 1, wave, lane);
  __syncthreads();                                // (6) h2 reads done
  epilogue_relu(c0, Act0, wave, lane);
  epilogue_relu(c1, Act1, wave, lane);
  __syncthreads();                                // (7) Act = h3

  mfma_L4(wr, w4b, Act0, Act1, b4, c0, c1, wave, lane);      // layer 4
  {
    const int m = lane & 15, quad = lane >> 4;
    const float* mk = mask + (size_t)b*NPOS + n0;
    #pragma unroll
    for (int sd=0;sd<2;sd++){
      const int d = wave*32 + sd*16 + m;
      ushort_t* rowp = h4 + ((size_t)b*CO + d)*NPOS + n0;
      #pragma unroll
      for (int sn=0;sn<4;sn++){
        float4 mr0 = *(const float4*)(mk + sn*16 + quad*4);
        float4 mr1 = *(const float4*)(mk + 64 + sn*16 + quad*4);
        unsigned q0 = cvtpk_u32(c0[sn][sd][0] * (1.0f/512.0f) * mr0.x,
                                c0[sn][sd][1] * (1.0f/512.0f) * mr0.y);
        unsigned q1 = cvtpk_u32(c0[sn][sd][2] * (1.0f/512.0f) * mr0.z,
                                c0[sn][sd][3] * (1.0f/512.0f) * mr0.w);
        *(uint2*)(rowp + sn*16 + quad*4) = make_uint2(q0, q1);
        unsigned p0 = cvtpk_u32(c1[sn][sd][0] * (1.0f/512.0f) * mr1.x,
                                c1[sn][sd][1] * (1.0f/512.0f) * mr1.y);
        unsigned p1 = cvtpk_u32(c1[sn][sd][2] * (1.0f/512.0f) * mr1.z,
                                c1[sn][sd][3] * (1.0f/512.0f) * mr1.w);
        *(uint2*)(rowp + 64 + sn*16 + quad*4) = make_uint2(p0, p1);
      }
    }
  }
}

// ---------------- sort + pool (+ size feature fold) ----------------
// Packed bitonic, TWO rows per wave (row0 low u16 / row1 high u16 of 8 regs).
// xor 1,2,8 via DPP (VALU pipe); 4,16,32 via __shfl_xor. Direction-flip trick
// makes every CE fixed-ascending. Weight lookup from precomputed Wt.

static __device__ __forceinline__ void ce_up(unsigned &a, unsigned &b){
  unsigned mn = pk_min_u16(a,b), mx = pk_max_u16(a,b); a = mn; b = mx;
}
static __device__ __forceinline__ void ce_dn(unsigned &a, unsigned &b){
  unsigned mn = pk_min_u16(a,b), mx = pk_max_u16(a,b); a = mx; b = mn;
}
static __device__ __forceinline__ void clean8(unsigned (&v)[8]){   // j=4,2,1 ascending
  ce_up(v[0],v[4]); ce_up(v[1],v[5]); ce_up(v[2],v[6]); ce_up(v[3],v[7]);
  ce_up(v[0],v[2]); ce_up(v[1],v[3]); ce_up(v[4],v[6]); ce_up(v[5],v[7]);
  ce_up(v[0],v[1]); ce_up(v[2],v[3]); ce_up(v[4],v[5]); ce_up(v[6],v[7]);
}
static __device__ __forceinline__ void flip8(unsigned (&v)[8], unsigned f){
  #pragma unroll
  for (int i=0;i<8;i++) v[i] ^= f;
}
template<int CTRL>
static __device__ __forceinline__ void xr_dpp(unsigned (&v)[8], bool low){
  #pragma unroll
  for (int i=0;i<8;i++){
    unsigned p = mov_dpp_u32<CTRL>(v[i]);
    unsigned mn = pk_min_u16(v[i], p), mx = pk_max_u16(v[i], p);
    v[i] = low ? mn : mx;
  }
}
static __device__ __forceinline__ void xr_shfl(unsigned (&v)[8], int lm, bool low){
  #pragma unroll
  for (int i=0;i<8;i++){
    unsigned p = (unsigned)__shfl_xor((int)v[i], lm);
    unsigned mn = pk_min_u16(v[i], p), mx = pk_max_u16(v[i], p);
    v[i] = low ? mn : mx;
  }
}

__global__ void k_pool(const ushort_t* __restrict__ h4, const float* __restrict__ Wt,
                       const float* __restrict__ mask, float* __restrict__ out)
{
  const int lane = threadIdx.x & 63;
  const int wave = threadIdx.x >> 6;
  const size_t r0 = (size_t)blockIdx.x*8 + wave*2;   // rows r0, r0+1
  const int b0 = (int)(r0 >> 7), c0 = (int)(r0 & 127);
  const int b1_ = (int)((r0+1) >> 7), c1 = (int)((r0+1) & 127);

  uint4 ra = *(const uint4*)(h4 + r0*NPOS     + lane*8);
  uint4 rb = *(const uint4*)(h4 + (r0+1)*NPOS + lane*8);

  unsigned v[8];
  v[0] = (ra.x & 0xFFFFu) | (rb.x << 16);
  v[1] = (ra.x >> 16)     | (rb.x & 0xFFFF0000u);
  v[2] = (ra.y & 0xFFFFu) | (rb.y << 16);
  v[3] = (ra.y >> 16)     | (rb.y & 0xFFFF0000u);
  v[4] = (ra.z & 0xFFFFu) | (rb.z << 16);
  v[5] = (ra.z >> 16)     | (rb.z & 0xFFFF0000u);
  v[6] = (ra.w & 0xFFFFu) | (rb.w << 16);
  v[7] = (ra.w >> 16)     | (rb.w & 0xFFFF0000u);

  // bf16 -> sortable u16 key (both halves at once)
  #pragma unroll
  for (int i=0;i<8;i++){
    unsigned sb = (v[i] >> 15) & 0x00010001u;
    v[i] = v[i] ^ 0x80008000u ^ (sb * 0x7FFFu);
  }

  const bool lo1  = (lane & 1)  == 0;
  const bool lo2  = (lane & 2)  == 0;
  const bool lo4  = (lane & 4)  == 0;
  const bool lo8  = (lane & 8)  == 0;
  const bool lo16 = (lane & 16) == 0;
  const bool lo32 = (lane & 32) == 0;

  const unsigned F8   = (lane & 1)  ? 0xFFFFFFFFu : 0u;
  const unsigned F16  = (lane & 2)  ? 0xFFFFFFFFu : 0u;
  const unsigned F32  = (lane & 4)  ? 0xFFFFFFFFu : 0u;
  const unsigned F64  = (lane & 8)  ? 0xFFFFFFFFu : 0u;
  const unsigned F128 = (lane & 16) ? 0xFFFFFFFFu : 0u;
  const unsigned F256 = (lane & 32) ? 0xFFFFFFFFu : 0u;

  // k=2, k=4 presort (fixed directions)
  ce_up(v[0],v[1]); ce_dn(v[2],v[3]); ce_up(v[4],v[5]); ce_dn(v[6],v[7]);
  ce_up(v[0],v[2]); ce_up(v[1],v[3]); ce_dn(v[4],v[6]); ce_dn(v[5],v[7]);
  ce_up(v[0],v[1]); ce_up(v[2],v[3]); ce_dn(v[4],v[5]); ce_dn(v[6],v[7]);

  flip8(v, F8);                                   // k=8 (in-lane only)
  clean8(v);
  flip8(v, F8 ^ F16);                             // k=16
  xr_dpp<0xB1>(v, lo1);
  clean8(v);
  flip8(v, F16 ^ F32);                            // k=32
  xr_dpp<0x4E>(v, lo2); xr_dpp<0xB1>(v, lo1);
  clean8(v);
  flip8(v, F32 ^ F64);                            // k=64
  xr_shfl(v, 4, lo4); xr_dpp<0x4E>(v, lo2); xr_dpp<0xB1>(v, lo1);
  clean8(v);
  flip8(v, F64 ^ F128);                           // k=128
  xr_dpp<0x128>(v, lo8); xr_shfl(v, 4, lo4); xr_dpp<0x4E>(v, lo2); xr_dpp<0xB1>(v, lo1);
  clean8(v);
  flip8(v, F128 ^ F256);                          // k=256
  xr_shfl(v, 16, lo16); xr_dpp<0x128>(v, lo8); xr_shfl(v, 4, lo4);
  xr_dpp<0x4E>(v, lo2); xr_dpp<0xB1>(v, lo1);
  clean8(v);
  flip8(v, F256);                                 // k=512 runs unflipped
  xr_shfl(v, 32, lo32); xr_shfl(v, 16, lo16); xr_dpp<0x128>(v, lo8);
  xr_shfl(v, 4, lo4); xr_dpp<0x4E>(v, lo2); xr_dpp<0xB1>(v, lo1);
  clean8(v);

  // key -> bf16 bits (both halves)
  #pragma unroll
  for (int i=0;i<8;i++){
    unsigned sb = ((~v[i]) >> 15) & 0x00010001u;
    v[i] = v[i] ^ 0x80008000u ^ (sb * 0x7FFFu);
  }

  // dot with precomputed weights (ascending position i = lane*8 + reg)
  float w0[8], w1a[8];
  *(float4*)&w0[0]  = *(const float4*)(Wt + c0*512 + lane*8);
  *(float4*)&w0[4]  = *(const float4*)(Wt + c0*512 + lane*8 + 4);
  *(float4*)&w1a[0] = *(const float4*)(Wt + c1*512 + lane*8);
  *(float4*)&w1a[4] = *(const float4*)(Wt + c1*512 + lane*8 + 4);

  float s0 = 0.f, s1 = 0.f;
  #pragma unroll
  for (int i=0;i<8;i++){
    union {unsigned u; float f;} lo, hi;
    lo.u = v[i] << 16;
    hi.u = v[i] & 0xFFFF0000u;
    s0 = fmaf(lo.f, w0[i],  s0);
    s1 = fmaf(hi.f, w1a[i], s1);
  }
  s0 = fadd_dpp<0xB1>(s0);  s1 = fadd_dpp<0xB1>(s1);
  s0 = fadd_dpp<0x4E>(s0);  s1 = fadd_dpp<0x4E>(s1);
  s0 = fadd_dpp<0x128>(s0); s1 = fadd_dpp<0x128>(s1);
  s0 += __shfl_xor(s0, 4);  s1 += __shfl_xor(s1, 4);
  s0 += __shfl_xor(s0, 16); s1 += __shfl_xor(s1, 16);
  s0 += __shfl_xor(s0, 32); s1 += __shfl_xor(s1, 32);

  if (lane == 0){
    out[b0*129 + c0]  = s0;
    out[b1_*129 + c1] = s1;
  }

  // folded size feature: blocks 0..1023, wave 0 compute out[b,128]
  if (blockIdx.x < 1024 && wave == 0){
    const int b = blockIdx.x;
    float s = 0.f;
    #pragma unroll
    for (int i=0;i<2;i++){
      float4 mv = *(const float4*)(mask + (size_t)b*NPOS + lane*8 + i*4);
      s += mv.x + mv.y + mv.z + mv.w;
    }
    s = fadd_dpp<0xB1>(s); s = fadd_dpp<0x4E>(s); s = fadd_dpp<0x128>(s);
    s += __shfl_xor(s, 4); s += __shfl_xor(s, 16); s += __shfl_xor(s, 32);
    if (lane == 0) out[b*129 + 128] = s * (1.0f/128.0f);  // mean*4 = sum/512*4
  }
}

extern "C" void kernel_launch(void* const* d_in, const int* in_sizes, int n_in,
                              void* d_out, int out_size, void* d_ws, size_t ws_size,
                              hipStream_t stream){
  const float* x    = (const float*)d_in[0];
  const float* mask = (const float*)d_in[1];
  const float* w1   = (const float*)d_in[2];
  const float* b1   = (const float*)d_in[3];
  const float* w2   = (const float*)d_in[4];
  const float* b2   = (const float*)d_in[5];
  const float* w3   = (const float*)d_in[6];
  const float* b3   = (const float*)d_in[7];
  const float* w4   = (const float*)d_in[8];
  const float* b4   = (const float*)d_in[9];
  const float* pw   = (const float*)d_in[10];
  float* out = (float*)d_out;

  // ws: h4 bf16 (1024*128*512 = 128MB) | w2b | w3b | w4b | w1b | Wt (f32 128x512)
  ushort_t* h4  = (ushort_t*)d_ws;
  ushort_t* w2b = h4 + (size_t)1024*CO*NPOS;
  ushort_t* w3b = w2b + 65536;
  ushort_t* w4b = w3b + 65536;
  ushort_t* w1b = w4b + 32768;
  float*    Wt  = (float*)(w1b + 8192);

  k_prep <<<928,   256, 0, stream>>>(w1, w2, w3, w4, pw, w2b, Wt);
  k_fused<<<4096,  256, 0, stream>>>(x, mask, w1b, b1, w2b, b2, w3b, b3, w4b, b4, h4);
  k_pool <<<16384, 256, 0, stream>>>(h4, Wt, mask, out);
}